// Round 12
// baseline (87.770 us; speedup 1.0000x reference)
//
#include <hip/hip_runtime.h>

#define BSZ 4096
#define D 1024
#define N2 8192
#define TEMPV 0.5f
// exp(x/T) = exp2(x * log2(e)/T)
#define EXPSCALE 2.8853900817779268f
#define NTB 32      // 8192 / 256 tiles per dim

typedef __attribute__((ext_vector_type(8))) short bf16x8;
typedef __attribute__((ext_vector_type(4))) float f32x4;
typedef __attribute__((ext_vector_type(4))) int i32x4;
typedef __attribute__((ext_vector_type(8))) int i32x8;

__device__ inline unsigned short f2bf(float x) {
  unsigned int u = __float_as_uint(x);
  u += 0x7fffu + ((u >> 16) & 1u);   // round-to-nearest-even
  return (unsigned short)(u >> 16);
}

// bit-exact float -> OCP e4m3fn, RNE (inputs |x|<=1 here; clamp kept for safety)
__device__ inline unsigned int f2e4m3(float x) {
  unsigned int u = __float_as_uint(x);
  const unsigned int s = (u >> 24) & 0x80u;
  u &= 0x7fffffffu;
  const float a = __uint_as_float(u);
  if (a >= 448.0f) return s | 0x7Eu;
  if (a < 0.015625f) {                       // < 2^-6: subnormal
    const int m = (int)rintf(a * 512.0f);    // RNE; 8 -> 0x08 == 2^-6 exactly
    return s | (unsigned int)m;
  }
  u += 0x7FFFFu + ((u >> 20) & 1u);          // RNE to 3 mantissa bits
  const unsigned int e = u >> 23;            // biased f32 exp (>=121)
  const unsigned int m3 = (u >> 20) & 7u;
  return s | (((e - 120u) << 3) | m3);       // e4m3 bias 7
}

__device__ inline void gload16(const void* g, void* l) {
  __builtin_amdgcn_global_load_lds(
      (const __attribute__((address_space(1))) void*)g,
      (__attribute__((address_space(3))) void*)l, 16, 0, 0);
}

// ---------------- Kernel A: L2-normalize rows, emit bf16 + plain fp8 reps --------------
__global__ __launch_bounds__(256) void knorm(const float* __restrict__ ei,
                                             const float* __restrict__ ej,
                                             unsigned short* __restrict__ reps,
                                             unsigned char* __restrict__ reps8,
                                             float* __restrict__ pos) {
  const int r = blockIdx.x;
  const int t = threadIdx.x;
  const float4 vi = ((const float4*)(ei + (size_t)r * D))[t];
  const float4 vj = ((const float4*)(ej + (size_t)r * D))[t];
  float ssi = vi.x * vi.x + vi.y * vi.y + vi.z * vi.z + vi.w * vi.w;
  float ssj = vj.x * vj.x + vj.y * vj.y + vj.z * vj.z + vj.w * vj.w;
  float sij = vi.x * vj.x + vi.y * vj.y + vi.z * vj.z + vi.w * vj.w;
#pragma unroll
  for (int o = 32; o > 0; o >>= 1) {
    ssi += __shfl_xor(ssi, o);
    ssj += __shfl_xor(ssj, o);
    sij += __shfl_xor(sij, o);
  }
  __shared__ float red[12];
  const int lane = t & 63, wid = t >> 6;
  if (lane == 0) { red[wid * 3] = ssi; red[wid * 3 + 1] = ssj; red[wid * 3 + 2] = sij; }
  __syncthreads();
  ssi = red[0] + red[3] + red[6] + red[9];
  ssj = red[1] + red[4] + red[7] + red[10];
  sij = red[2] + red[5] + red[8] + red[11];
  const float inv_i = rsqrtf(fmaxf(ssi, 1e-24f));
  const float inv_j = rsqrtf(fmaxf(ssj, 1e-24f));
  const float xi0 = vi.x * inv_i, xi1 = vi.y * inv_i, xi2 = vi.z * inv_i, xi3 = vi.w * inv_i;
  const float xj0 = vj.x * inv_j, xj1 = vj.y * inv_j, xj2 = vj.z * inv_j, xj3 = vj.w * inv_j;
  ushort4 ui, uj;
  ui.x = f2bf(xi0); ui.y = f2bf(xi1); ui.z = f2bf(xi2); ui.w = f2bf(xi3);
  uj.x = f2bf(xj0); uj.y = f2bf(xj1); uj.z = f2bf(xj2); uj.w = f2bf(xj3);
  *((ushort4*)(reps + (size_t)r * D) + t) = ui;
  *((ushort4*)(reps + (size_t)(BSZ + r) * D) + t) = uj;
  const unsigned int pi = f2e4m3(xi0) | (f2e4m3(xi1) << 8) | (f2e4m3(xi2) << 16) | (f2e4m3(xi3) << 24);
  const unsigned int pj = f2e4m3(xj0) | (f2e4m3(xj1) << 8) | (f2e4m3(xj2) << 16) | (f2e4m3(xj3) << 24);
  *(unsigned int*)(reps8 + (size_t)r * 1024 + t * 4) = pi;
  *(unsigned int*)(reps8 + (size_t)(BSZ + r) * 1024 + t * 4) = pj;
  if (t == 0) pos[r] = sij * inv_i * inv_j;
}

// ======================= shared asm helpers =======================
#define BARRIER() do { __builtin_amdgcn_s_barrier(); asm volatile("" ::: "memory"); } while (0)
#define STR2(x) #x
#define WAITV(n) asm volatile("s_waitcnt vmcnt(" STR2(n) ")" ::: "memory")
#define LGKM0() asm volatile("s_waitcnt lgkmcnt(0)" ::: "memory")

// ---------------- Kernel B: 256x256 tiles, MX-scaled fp8 (unit scales), BK=128 ----------
// 8 waves (2M x 4N), wave tile 128x64. LDS 128 KiB: A dbuf 2x32KB + B dbuf 2x32KB,
// rows = 128B fp8, chunk XOR swizzle LDS[row][c] = orig[row][c ^ (row&7)].
// MFMA: mfma_scale_f32_16x16x128_f8f6f4, FMT=0 (e4m3), scales 0x7F7F7F7F (=1.0).
// launch_bounds(512,1): LDS already caps at 1 block/CU; give allocator 256 VGPRs
// (R11's (512,2) forced a 128-VGPR cap -> 36 MB scratch spills per dispatch).
// Ledger/tile (4 A gloads @ph1 for t+1, 4 B gloads @ph3 for t+2): WAITV(4) at ph3
// retires A(t+1)+B(t+1) before ph4 reads them. Tile 6: WAITV(0). Prologue: WAITV(4).
#define SG_A(ii, ktv, dst) gload16(reps8 + (size_t)(arow0 + (ii) * 64 + (t >> 3)) * 1024 + \
                                       (ktv) * 128 + (((t & 7) ^ ((t >> 3) & 7)) << 4),    \
                                   (dst) + (size_t)(ii) * 8192 + (size_t)t * 16)
#define SG_B(ii, ktv, dst) gload16(reps8 + (size_t)(brow0 + (ii) * 64 + (t >> 3)) * 1024 + \
                                       (ktv) * 128 + (((t & 7) ^ ((t >> 3) & 7)) << 4),    \
                                   (dst) + (size_t)(ii) * 8192 + (size_t)t * 16)

#define READ_A2(buf, p) do {                                            \
    _Pragma("unroll") for (int m2_ = 0; m2_ < 2; m2_++) {               \
      const char* rp_ = (buf) + (size_t)(arow + ((p) * 2 + m2_) * 16) * 128; \
      i32x4 lo_ = *(const i32x4*)(rp_ + off0);                          \
      i32x4 hi_ = *(const i32x4*)(rp_ + off1);                          \
      afp[m2_] = __builtin_shufflevector(lo_, hi_, 0, 1, 2, 3, 4, 5, 6, 7); \
    }                                                                   \
  } while (0)

#define READ_B2(buf, n) do {                                            \
    const char* rp_ = (buf) + (size_t)(brow + (n) * 16) * 128;          \
    i32x4 lo_ = *(const i32x4*)(rp_ + off0);                            \
    i32x4 hi_ = *(const i32x4*)(rp_ + off1);                            \
    bfp[n] = __builtin_shufflevector(lo_, hi_, 0, 1, 2, 3, 4, 5, 6, 7); \
  } while (0)

// 8 scaled MFMA (K=128 each); bfp[0..1] half first so ph1's fresh bfp[2..3] have cover.
#define MFMA_P(p)                                                       \
  __builtin_amdgcn_s_setprio(1);                                        \
  _Pragma("unroll") for (int nh = 0; nh < 2; nh++)                      \
  _Pragma("unroll") for (int m2 = 0; m2 < 2; m2++)                      \
  _Pragma("unroll") for (int nn = 0; nn < 2; nn++) {                    \
    const int n_ = nh * 2 + nn;                                         \
    acc[2 * (p) + m2][n_] = __builtin_amdgcn_mfma_scale_f32_16x16x128_f8f6f4( \
        afp[m2], bfp[n_], acc[2 * (p) + m2][n_],                        \
        0, 0, 0, 0x7F7F7F7F, 0, 0x7F7F7F7F);                            \
  }                                                                     \
  __builtin_amdgcn_s_setprio(0);

#define DO_TILE(ktv, SA, SB, RDN, HASW, WV)                             \
  {                                                                     \
    const int cur = (ktv) & 1;                                          \
    const char* bA  = cur ? lA1 : lA0;                                  \
    const char* bB  = cur ? lB1 : lB0;                                  \
    const char* bAn = cur ? lA0 : lA1;                                  \
    const char* bBn = cur ? lB0 : lB1;                                  \
    char* stA = (char*)(cur ? lA0 : lA1);                               \
    char* stB = (char*)(cur ? lB1 : lB0);                               \
    /* ph1: P0 MFMA (ops from prev ph4); read bfp[2..3](t) + A frags 2,3; stage A(t+1) */ \
    READ_B2(bB, 2); READ_B2(bB, 3);                                     \
    MFMA_P(0);                                                          \
    READ_A2(bA, 1);                                                     \
    if (SA) { SG_A(0, (ktv) + 1, stA); SG_A(1, (ktv) + 1, stA);         \
              SG_A(2, (ktv) + 1, stA); SG_A(3, (ktv) + 1, stA); }       \
    BARRIER();                                                          \
    /* ph2 */                                                           \
    MFMA_P(1);                                                          \
    READ_A2(bA, 2);                                                     \
    BARRIER();                                                          \
    /* ph3: stage B(t+2); counted wait */                               \
    MFMA_P(2);                                                          \
    READ_A2(bA, 3);                                                     \
    if (SB) { SG_B(0, (ktv) + 2, stB); SG_B(1, (ktv) + 2, stB);         \
              SG_B(2, (ktv) + 2, stB); SG_B(3, (ktv) + 2, stB); }       \
    if (HASW) { WAITV(WV); }                                            \
    BARRIER();                                                          \
    /* ph4: read next tile's A frags 0,1 + bfp[0..1] */                 \
    MFMA_P(3);                                                          \
    if (RDN) { READ_A2(bAn, 0); READ_B2(bBn, 0); READ_B2(bBn, 1); }     \
    BARRIER();                                                          \
  }

__global__ __launch_bounds__(512, 1) void kgemm3(const unsigned char* __restrict__ reps8,
                                                 float* __restrict__ partial) {
  extern __shared__ char smem[];
  char* lA0 = smem;                           // 32 KB  [256 rows][128 B]
  char* lA1 = smem + 32768;
  char* lB0 = smem + 65536;
  char* lB1 = smem + 98304;

  // XCD-aware swizzle (512 = 8 * 64, bijective), then decode into the
  // 512-tile list: triangle minus tiles (0, 16..31).
  int bid = (int)blockIdx.x;
  bid = (bid & 7) * 64 + (bid >> 3);
  int rb, cb;
  if (bid < 16) {
    rb = 0; cb = bid;
  } else {
    int rem = bid - 16;
    rb = 1;
    while (rem >= NTB - rb) { rem -= NTB - rb; rb++; }
    cb = rb + rem;
  }

  const int t = threadIdx.x;
  const int l = t & 63, w = t >> 6;
  const int wr = w >> 2, wc = w & 3;          // 2 x 4 wave grid

  f32x4 acc[8][4];
  const f32x4 zero4 = {0.f, 0.f, 0.f, 0.f};
#pragma unroll
  for (int m = 0; m < 8; m++)
#pragma unroll
    for (int n = 0; n < 4; n++) acc[m][n] = zero4;

  const size_t arow0 = (size_t)rb * 256;
  const size_t brow0 = (size_t)cb * 256;

  // read-side: lane q-group holds orig chunks {2q, 2q+1}; LDS pos = chunk ^ (row&7)
  const int q2 = (l >> 4) & 3;
  const int arow = wr * 128 + (l & 15);
  const int brow = wc * 64 + (l & 15);
  const int r7 = l & 7;                       // == arow&7 == brow&7
  const int off0 = ((2 * q2) ^ r7) << 4;
  const int off1 = ((2 * q2 + 1) ^ r7) << 4;

  // ---- prologue: B(0), A(0), B(1); retire B(0)+A(0); preload tile-0 ph1 ops ----
  SG_B(0, 0, lB0); SG_B(1, 0, lB0); SG_B(2, 0, lB0); SG_B(3, 0, lB0);
  SG_A(0, 0, lA0); SG_A(1, 0, lA0); SG_A(2, 0, lA0); SG_A(3, 0, lA0);
  SG_B(0, 1, lB1); SG_B(1, 1, lB1); SG_B(2, 1, lB1); SG_B(3, 1, lB1);
  WAITV(4);
  BARRIER();

  i32x8 afp[2], bfp[4];
  READ_A2(lA0, 0);
  READ_B2(lB0, 0);
  READ_B2(lB0, 1);

#pragma unroll 1
  for (int kt = 0; kt < 6; ++kt) DO_TILE(kt, 1, 1, 1, 1, 4)
  DO_TILE(6, 1, 0, 1, 1, 0)
  DO_TILE(7, 0, 0, 0, 0, 0)

  // -------- epilogue: exp + diagonal mask + row/col partial sums --------
  float rsum[8][4];
  float csum[4];
#pragma unroll
  for (int m = 0; m < 8; m++)
#pragma unroll
    for (int j = 0; j < 4; j++) rsum[m][j] = 0.f;
#pragma unroll
  for (int n = 0; n < 4; n++) csum[n] = 0.f;

  const int col16 = l & 15, rgp = (l >> 4) & 3;
  const bool diag = (rb == cb);
  const int growbase = wr * 128 + rgp * 4;
  const int gcolbase = wc * 64 + col16;
#pragma unroll
  for (int m = 0; m < 8; m++) {
#pragma unroll
    for (int n = 0; n < 4; n++) {
#pragma unroll
      for (int j = 0; j < 4; j++) {
        const float e = (diag && (growbase + m * 16 + j) == (gcolbase + n * 16))
                            ? 0.f
                            : exp2f(acc[m][n][j] * EXPSCALE);
        rsum[m][j] += e;
        csum[n] += e;
      }
    }
  }
#pragma unroll
  for (int m = 0; m < 8; m++)
#pragma unroll
    for (int j = 0; j < 4; j++) {
      float v = rsum[m][j];
      v += __shfl_xor(v, 1); v += __shfl_xor(v, 2);
      v += __shfl_xor(v, 4); v += __shfl_xor(v, 8);
      rsum[m][j] = v;
    }
#pragma unroll
  for (int n = 0; n < 4; n++) {
    float v = csum[n];
    v += __shfl_xor(v, 16); v += __shfl_xor(v, 32);
    csum[n] = v;
  }

  float* rS = (float*)smem;            // [4 wc][256 rows]
  float* cS = ((float*)smem) + 1024;   // [2 wr][256 cols]
  if (col16 == 0) {
#pragma unroll
    for (int m = 0; m < 8; m++)
#pragma unroll
      for (int j = 0; j < 4; j++)
        rS[wc * 256 + wr * 128 + m * 16 + rgp * 4 + j] = rsum[m][j];
  }
  if (rgp == 0) {
#pragma unroll
    for (int n = 0; n < 4; n++)
      cS[wr * 256 + wc * 64 + n * 16 + col16] = csum[n];
  }
  __syncthreads();
  // partial layout: [68 col-blocks of 128][8192 rows]
  if (t < 256) {
    const float rs_lo = rS[t] + rS[256 + t];
    const float rs_hi = rS[512 + t] + rS[768 + t];
    partial[(size_t)(cb * 2) * N2 + rb * 256 + t] = rs_lo;
    partial[(size_t)(cb * 2 + 1) * N2 + rb * 256 + t] = rs_hi;
    if (!diag) {
      partial[(size_t)(rb * 2) * N2 + cb * 256 + t] = cS[t];
      partial[(size_t)(rb * 2 + 1) * N2 + cb * 256 + t] = cS[256 + t];
    }
  }
}

// ---------------- Kernel Bt: tail — 128 eighth-tiles (64x128) of tiles (0,16..31) -------
// bf16, unchanged (reads the bf16 reps copy).
#define TSG_A(ii, ktv, dst) gload16(reps + (tarow0 + (ii) * 32 + tsrow) * D + (ktv) * 128 + tschk * 8, \
                                    (dst) + (size_t)((ii) * 32 + w * 4) * 128)
#define TSG_B(ii, ktv, dst) gload16(reps + (tbrow0 + (ii) * 32 + tsrow) * D + (ktv) * 128 + tschk * 8, \
                                    (dst) + (size_t)((ii) * 32 + w * 4) * 128)

#define TRD(buf, row, kk) (*(const bf16x8*)((const char*)(buf) + (row) * 256 + \
                           ((((kk) * 4 + q4) ^ ((row) & 15)) << 4)))

#define TMFMA(kk)                                                       \
  __builtin_amdgcn_s_setprio(1);                                        \
  _Pragma("unroll") for (int m2 = 0; m2 < 2; m2++)                      \
  _Pragma("unroll") for (int n = 0; n < 2; n++)                         \
    acc[m2][n] = __builtin_amdgcn_mfma_f32_16x16x32_bf16(               \
        af[m2][kk], bf[n][kk], acc[m2][n], 0, 0, 0);                    \
  __builtin_amdgcn_s_setprio(0);

#define TTILE(tv, S, R, HASW, WV)                                       \
  {                                                                     \
    const int cur = (tv) & 1;                                           \
    const char* bA  = cur ? (const char*)tA1 : (const char*)tA0;        \
    const char* bB  = cur ? (const char*)tB1 : (const char*)tB0;        \
    const char* bAn = cur ? (const char*)tA0 : (const char*)tA1;        \
    const char* bBn = cur ? (const char*)tB0 : (const char*)tB1;        \
    short* stA = cur ? tA1 : tA0;   /* = bA buffer: parity(t+2) */      \
    short* stB = cur ? tB1 : tB0;                                       \
    _Pragma("unroll") for (int kk = 2; kk < 4; kk++) {                  \
      _Pragma("unroll") for (int m2 = 0; m2 < 2; m2++)                  \
        af[m2][kk] = TRD(bA, tarow_r + m2 * 16, kk);                    \
      _Pragma("unroll") for (int n = 0; n < 2; n++)                     \
        bf[n][kk] = TRD(bB, tbrow_r + n * 16, kk);                      \
    }                                                                   \
    TMFMA(0); TMFMA(1);                                                 \
    LGKM0();                                                            \
    BARRIER();                                                          \
    if (S) { TSG_A(0, (tv) + 2, stA); TSG_A(1, (tv) + 2, stA);          \
             TSG_B(0, (tv) + 2, stB); TSG_B(1, (tv) + 2, stB);          \
             TSG_B(2, (tv) + 2, stB); TSG_B(3, (tv) + 2, stB); }        \
    TMFMA(2); TMFMA(3);                                                 \
    if (HASW) { WAITV(WV); }                                            \
    BARRIER();                                                          \
    if (R) {                                                            \
      _Pragma("unroll") for (int kk = 0; kk < 2; kk++) {                \
        _Pragma("unroll") for (int m2 = 0; m2 < 2; m2++)                \
          af[m2][kk] = TRD(bAn, tarow_r + m2 * 16, kk);                 \
        _Pragma("unroll") for (int n = 0; n < 2; n++)                   \
          bf[n][kk] = TRD(bBn, tbrow_r + n * 16, kk);                   \
      }                                                                 \
    }                                                                   \
  }

__global__ __launch_bounds__(512) void kgemmt(const short* __restrict__ reps,
                                              float* __restrict__ partial) {
  extern __shared__ char smem[];
  short* tA0 = (short*)smem;                  // 16 KB [64][128]
  short* tA1 = (short*)(smem + 16384);
  short* tB0 = (short*)(smem + 32768);        // 32 KB [128][128]
  short* tB1 = (short*)(smem + 65536);

  const int b = (int)blockIdx.x;              // 0..127
  const int s = b >> 3, sub = b & 7;
  const int qr = sub >> 1;                    // 64-row chunk of rows 0..255
  const int qc = sub & 1;                     // 128-col half of the 256-col tile
  const int cbt = 16 + s;

  const int t = threadIdx.x;
  const int l = t & 63, w = t >> 6;
  const int wr = w >> 2, wc = w & 3;          // 2 x 4 wave grid

  f32x4 acc[2][2];
  const f32x4 zero4 = {0.f, 0.f, 0.f, 0.f};
#pragma unroll
  for (int m = 0; m < 2; m++)
#pragma unroll
    for (int n = 0; n < 2; n++) acc[m][n] = zero4;

  const int tsrow = w * 4 + (l >> 4);          // row within 32-row inst chunk
  const int tschk = (l & 15) ^ (tsrow & 15);   // pre-swizzled source 16B chunk
  const size_t tarow0 = (size_t)qr * 64;
  const size_t tbrow0 = (size_t)cbt * 256 + (size_t)qc * 128;

  const int q4 = (l >> 4) & 3;
  const int tarow_r = wr * 32 + (l & 15);
  const int tbrow_r = wc * 32 + (l & 15);

  TSG_A(0, 0, tA0); TSG_A(1, 0, tA0);
  TSG_B(0, 0, tB0); TSG_B(1, 0, tB0); TSG_B(2, 0, tB0); TSG_B(3, 0, tB0);
  TSG_A(0, 1, tA1); TSG_A(1, 1, tA1);
  TSG_B(0, 1, tB1); TSG_B(1, 1, tB1); TSG_B(2, 1, tB1); TSG_B(3, 1, tB1);
  WAITV(6);
  BARRIER();

  bf16x8 af[2][4], bf[2][4];
#pragma unroll
  for (int kk = 0; kk < 2; kk++) {
#pragma unroll
    for (int m2 = 0; m2 < 2; m2++) af[m2][kk] = TRD((const char*)tA0, tarow_r + m2 * 16, kk);
#pragma unroll
    for (int n = 0; n < 2; n++) bf[n][kk] = TRD((const char*)tB0, tbrow_r + n * 16, kk);
  }

#pragma unroll 1
  for (int tv = 0; tv < 6; ++tv) TTILE(tv, 1, 1, 1, 6)
  TTILE(6, 0, 1, 1, 0)
  TTILE(7, 0, 0, 0, 0)

  float rsum[2][4];
  float csum[2];
#pragma unroll
  for (int m = 0; m < 2; m++)
#pragma unroll
    for (int j = 0; j < 4; j++) rsum[m][j] = 0.f;
  csum[0] = 0.f; csum[1] = 0.f;

#pragma unroll
  for (int m = 0; m < 2; m++)
#pragma unroll
    for (int n = 0; n < 2; n++)
#pragma unroll
      for (int j = 0; j < 4; j++) {
        const float e = exp2f(acc[m][n][j] * EXPSCALE);
        rsum[m][j] += e;
        csum[n] += e;
      }
#pragma unroll
  for (int m = 0; m < 2; m++)
#pragma unroll
    for (int j = 0; j < 4; j++) {
      float v = rsum[m][j];
      v += __shfl_xor(v, 1); v += __shfl_xor(v, 2);
      v += __shfl_xor(v, 4); v += __shfl_xor(v, 8);
      rsum[m][j] = v;
    }
#pragma unroll
  for (int n = 0; n < 2; n++) {
    float v = csum[n];
    v += __shfl_xor(v, 16); v += __shfl_xor(v, 32);
    csum[n] = v;
  }

  const int col16 = l & 15, rgp = (l >> 4) & 3;
  float* rS = (float*)smem;            // [4 wc][64 rows]
  float* cS = ((float*)smem) + 256;    // [2 wr][128 cols]
  if (col16 == 0) {
#pragma unroll
    for (int m = 0; m < 2; m++)
#pragma unroll
      for (int j = 0; j < 4; j++)
        rS[wc * 64 + wr * 32 + m * 16 + rgp * 4 + j] = rsum[m][j];
  }
  if (rgp == 0) {
#pragma unroll
    for (int n = 0; n < 2; n++)
      cS[wr * 128 + wc * 32 + n * 16 + col16] = csum[n];
  }
  __syncthreads();
  if (t < 64) {
    const float rs = rS[t] + rS[64 + t] + rS[128 + t] + rS[192 + t];
    partial[(size_t)(cbt * 2 + qc) * N2 + qr * 64 + t] = rs;
  }
  if (t < 128) {
    const float cs = cS[t] + cS[128 + t];
    partial[(size_t)(64 + qr) * N2 + cbt * 256 + qc * 128 + t] = cs;
  }
}

// ---------------- Kernel C1: per-row denom; log; block sum --------------------------------
__device__ inline float blockReduce(float v, float* sred) {
#pragma unroll
  for (int o = 32; o > 0; o >>= 1) v += __shfl_xor(v, o);
  const int lane = threadIdx.x & 63, wid = threadIdx.x >> 6;
  if (lane == 0) sred[wid] = v;
  __syncthreads();
  v = sred[0] + sred[1] + sred[2] + sred[3];
  __syncthreads();
  return v;
}

__global__ __launch_bounds__(256) void kred1(const float* __restrict__ partial,
                                             float* __restrict__ bsum) {
  const int r = blockIdx.x * 256 + threadIdx.x;
  float d = 0.f;
#pragma unroll 8
  for (int cbx = 0; cbx < 64; ++cbx) d += partial[(size_t)cbx * N2 + r];
  if (blockIdx.x >= 16) {   // rows >= 4096: add tail colsum slots 64..67
#pragma unroll
    for (int cbx = 64; cbx < 68; ++cbx) d += partial[(size_t)cbx * N2 + r];
  }
  float v = logf(d);
  __shared__ float sred[4];
  v = blockReduce(v, sred);
  if (threadIdx.x == 0) bsum[blockIdx.x] = v;
}

// ---------------- Kernel C2: final scalar -------------------------------------------------
__global__ __launch_bounds__(256) void kred2(const float* __restrict__ bsum,
                                             const float* __restrict__ pos,
                                             float* __restrict__ out) {
  const int t = threadIdx.x;
  float v = (t < 32) ? bsum[t] : 0.f;
  float p = 0.f;
  for (int k = t; k < BSZ; k += 256) p += pos[k];
  __shared__ float sred[4];
  v = blockReduce(v, sred);
  p = blockReduce(p, sred);
  if (t == 0) out[0] = (v - 2.0f * p / TEMPV) / (float)N2;
}

extern "C" void kernel_launch(void* const* d_in, const int* in_sizes, int n_in,
                              void* d_out, int out_size, void* d_ws, size_t ws_size,
                              hipStream_t stream) {
  const float* ei = (const float*)d_in[0];
  const float* ej = (const float*)d_in[1];
  char* ws = (char*)d_ws;
  unsigned short* reps = (unsigned short*)ws;                          // 16 MB bf16 [8192][1024]
  unsigned char* reps8 = (unsigned char*)(ws + (size_t)16 * 1024 * 1024); // 8 MB fp8 (plain)
  float* partial = (float*)(ws + (size_t)24 * 1024 * 1024);            // 2.13 MB [68][8192]
  float* pos = (float*)(ws + (size_t)24 * 1024 * 1024 + 2304 * 1024);  // 16 KB [4096]
  float* bsum = (float*)(ws + (size_t)24 * 1024 * 1024 + 2304 * 1024 + 16384); // 128 B

  (void)hipFuncSetAttribute((const void*)kgemm3,
                            hipFuncAttributeMaxDynamicSharedMemorySize, 131072);
  (void)hipFuncSetAttribute((const void*)kgemmt,
                            hipFuncAttributeMaxDynamicSharedMemorySize, 98304);

  knorm<<<BSZ, 256, 0, stream>>>(ei, ej, reps, reps8, pos);
  kgemm3<<<512, 512, 131072, stream>>>(reps8, partial);
  kgemmt<<<128, 512, 98304, stream>>>((const short*)reps, partial);
  kred1<<<32, 256, 0, stream>>>(partial, bsum);
  kred2<<<1, 256, 0, stream>>>(bsum, pos, (float*)d_out);
}

// Round 13
// 74.714 us; speedup vs baseline: 1.1747x; 1.1747x over previous
//
#include <hip/hip_runtime.h>

#define BSZ 4096
#define D 1024
#define N2 8192
#define TEMPV 0.5f
// exp(x/T) = exp2(x * log2(e)/T)
#define EXPSCALE 2.8853900817779268f
#define NTB 32      // 8192 / 256 tiles per dim

typedef __attribute__((ext_vector_type(8))) short bf16x8;
typedef __attribute__((ext_vector_type(4))) float f32x4;
typedef __attribute__((ext_vector_type(4))) int i32x4;
typedef __attribute__((ext_vector_type(8))) int i32x8;

__device__ inline unsigned short f2bf(float x) {
  unsigned int u = __float_as_uint(x);
  u += 0x7fffu + ((u >> 16) & 1u);   // round-to-nearest-even
  return (unsigned short)(u >> 16);
}

// bit-exact float -> OCP e4m3fn, RNE (inputs |x|<=1 here; clamp kept for safety)
__device__ inline unsigned int f2e4m3(float x) {
  unsigned int u = __float_as_uint(x);
  const unsigned int s = (u >> 24) & 0x80u;
  u &= 0x7fffffffu;
  const float a = __uint_as_float(u);
  if (a >= 448.0f) return s | 0x7Eu;
  if (a < 0.015625f) {                       // < 2^-6: subnormal
    const int m = (int)rintf(a * 512.0f);    // RNE; 8 -> 0x08 == 2^-6 exactly
    return s | (unsigned int)m;
  }
  u += 0x7FFFFu + ((u >> 20) & 1u);          // RNE to 3 mantissa bits
  const unsigned int e = u >> 23;            // biased f32 exp (>=121)
  const unsigned int m3 = (u >> 20) & 7u;
  return s | (((e - 120u) << 3) | m3);       // e4m3 bias 7
}

__device__ inline void gload16(const void* g, void* l) {
  __builtin_amdgcn_global_load_lds(
      (const __attribute__((address_space(1))) void*)g,
      (__attribute__((address_space(3))) void*)l, 16, 0, 0);
}

// ---------------- Kernel A: L2-normalize rows, emit bf16 + plain fp8 reps --------------
__global__ __launch_bounds__(256) void knorm(const float* __restrict__ ei,
                                             const float* __restrict__ ej,
                                             unsigned short* __restrict__ reps,
                                             unsigned char* __restrict__ reps8,
                                             float* __restrict__ pos) {
  const int r = blockIdx.x;
  const int t = threadIdx.x;
  const float4 vi = ((const float4*)(ei + (size_t)r * D))[t];
  const float4 vj = ((const float4*)(ej + (size_t)r * D))[t];
  float ssi = vi.x * vi.x + vi.y * vi.y + vi.z * vi.z + vi.w * vi.w;
  float ssj = vj.x * vj.x + vj.y * vj.y + vj.z * vj.z + vj.w * vj.w;
  float sij = vi.x * vj.x + vi.y * vj.y + vi.z * vj.z + vi.w * vj.w;
#pragma unroll
  for (int o = 32; o > 0; o >>= 1) {
    ssi += __shfl_xor(ssi, o);
    ssj += __shfl_xor(ssj, o);
    sij += __shfl_xor(sij, o);
  }
  __shared__ float red[12];
  const int lane = t & 63, wid = t >> 6;
  if (lane == 0) { red[wid * 3] = ssi; red[wid * 3 + 1] = ssj; red[wid * 3 + 2] = sij; }
  __syncthreads();
  ssi = red[0] + red[3] + red[6] + red[9];
  ssj = red[1] + red[4] + red[7] + red[10];
  sij = red[2] + red[5] + red[8] + red[11];
  const float inv_i = rsqrtf(fmaxf(ssi, 1e-24f));
  const float inv_j = rsqrtf(fmaxf(ssj, 1e-24f));
  const float xi0 = vi.x * inv_i, xi1 = vi.y * inv_i, xi2 = vi.z * inv_i, xi3 = vi.w * inv_i;
  const float xj0 = vj.x * inv_j, xj1 = vj.y * inv_j, xj2 = vj.z * inv_j, xj3 = vj.w * inv_j;
  ushort4 ui, uj;
  ui.x = f2bf(xi0); ui.y = f2bf(xi1); ui.z = f2bf(xi2); ui.w = f2bf(xi3);
  uj.x = f2bf(xj0); uj.y = f2bf(xj1); uj.z = f2bf(xj2); uj.w = f2bf(xj3);
  *((ushort4*)(reps + (size_t)r * D) + t) = ui;
  *((ushort4*)(reps + (size_t)(BSZ + r) * D) + t) = uj;
  const unsigned int pi = f2e4m3(xi0) | (f2e4m3(xi1) << 8) | (f2e4m3(xi2) << 16) | (f2e4m3(xi3) << 24);
  const unsigned int pj = f2e4m3(xj0) | (f2e4m3(xj1) << 8) | (f2e4m3(xj2) << 16) | (f2e4m3(xj3) << 24);
  *(unsigned int*)(reps8 + (size_t)r * 1024 + t * 4) = pi;
  *(unsigned int*)(reps8 + (size_t)(BSZ + r) * 1024 + t * 4) = pj;
  if (t == 0) pos[r] = sij * inv_i * inv_j;
}

// ======================= shared asm helpers =======================
#define BARRIER() do { __builtin_amdgcn_s_barrier(); asm volatile("" ::: "memory"); } while (0)
#define STR2(x) #x
#define WAITV(n) asm volatile("s_waitcnt vmcnt(" STR2(n) ")" ::: "memory")
#define LGKM0() asm volatile("s_waitcnt lgkmcnt(0)" ::: "memory")

// ---------------- Kernel B: 256x256 tiles, MX-scaled fp8 (unit scales), BK=128 ----------
// 8 waves (2M x 4N), wave tile 128x64. LDS 128 KiB: A dbuf @0/@16384, B dbuf @32768/@49152,
// rows = 128B fp8, chunk XOR swizzle LDS[row][c] = orig[row][c ^ (row&7)].
// MFMA: mfma_scale_f32_16x16x128_f8f6f4, FMT=0 (e4m3), scales 0x7F7F7F7F (=1.0).
// FULLY UNROLLED 8 K-tiles: all buffer parities & row offsets are compile-time
// constants folded into ds offsets (max 49152+3*2048+112 < 64KB) -> minimal arch-VGPR
// live set (R11/R12's (512,*) builds spilled ~33 regs: 36.8 MB scratch WRITE_SIZE).
// Ledger/tile (4 A gloads @ph1 for t+1, 4 B gloads @ph3 for t+2): WAITV(4) at ph3
// retires A(t+1)+B(t+1) before ph4 reads them. Tile 6: WAITV(0). Prologue: WAITV(4).
#define SG_A(ii, ktv, dst) gload16(reps8 + (size_t)(arow0 + (ii) * 64 + (t >> 3)) * 1024 + \
                                       (ktv) * 128 + (((t & 7) ^ ((t >> 3) & 7)) << 4),    \
                                   (dst) + (size_t)(ii) * 8192 + (size_t)t * 16)
#define SG_B(ii, ktv, dst) gload16(reps8 + (size_t)(brow0 + (ii) * 64 + (t >> 3)) * 1024 + \
                                       (ktv) * 128 + (((t & 7) ^ ((t >> 3) & 7)) << 4),    \
                                   (dst) + (size_t)(ii) * 8192 + (size_t)t * 16)

#define ABUF(c) ((c) ? 16384 : 0)
#define BBUF(c) ((c) ? 49152 : 32768)

#define READ_A2(bufoff, p) do {                                                       \
    i32x4 a0l = *(const i32x4*)(smem + (bufoff) + ((p) * 2) * 2048 + aaddr0);         \
    i32x4 a0h = *(const i32x4*)(smem + (bufoff) + ((p) * 2) * 2048 + aaddr1);         \
    i32x4 a1l = *(const i32x4*)(smem + (bufoff) + ((p) * 2 + 1) * 2048 + aaddr0);     \
    i32x4 a1h = *(const i32x4*)(smem + (bufoff) + ((p) * 2 + 1) * 2048 + aaddr1);     \
    afp[0] = __builtin_shufflevector(a0l, a0h, 0, 1, 2, 3, 4, 5, 6, 7);               \
    afp[1] = __builtin_shufflevector(a1l, a1h, 0, 1, 2, 3, 4, 5, 6, 7);               \
  } while (0)

#define READ_B2(bufoff, n) do {                                                       \
    i32x4 bl = *(const i32x4*)(smem + (bufoff) + (n) * 2048 + baddr0);                \
    i32x4 bh = *(const i32x4*)(smem + (bufoff) + (n) * 2048 + baddr1);                \
    bfp[n] = __builtin_shufflevector(bl, bh, 0, 1, 2, 3, 4, 5, 6, 7);                 \
  } while (0)

// 8 scaled MFMA (K=128 each); bfp[0..1] half first so ph1's fresh bfp[2..3] have cover.
#define MFMA_P(p)                                                       \
  __builtin_amdgcn_s_setprio(1);                                        \
  _Pragma("unroll") for (int nh = 0; nh < 2; nh++)                      \
  _Pragma("unroll") for (int m2 = 0; m2 < 2; m2++)                      \
  _Pragma("unroll") for (int nn = 0; nn < 2; nn++) {                    \
    const int n_ = nh * 2 + nn;                                         \
    acc[2 * (p) + m2][n_] = __builtin_amdgcn_mfma_scale_f32_16x16x128_f8f6f4( \
        afp[m2], bfp[n_], acc[2 * (p) + m2][n_],                        \
        0, 0, 0, 0x7F7F7F7F, 0, 0x7F7F7F7F);                            \
  }                                                                     \
  __builtin_amdgcn_s_setprio(0);

#define DO_TILE(ktv, SA, SB, RDN, HASW, WV)                             \
  {                                                                     \
    /* ph1: P0 MFMA (ops from prev ph4); read bfp[2..3](t) + A frags 2,3; stage A(t+1) */ \
    READ_B2(BBUF((ktv) & 1), 2); READ_B2(BBUF((ktv) & 1), 3);           \
    MFMA_P(0);                                                          \
    READ_A2(ABUF((ktv) & 1), 1);                                        \
    if (SA) { SG_A(0, (ktv) + 1, smem + ABUF(((ktv) + 1) & 1));         \
              SG_A(1, (ktv) + 1, smem + ABUF(((ktv) + 1) & 1));         \
              SG_A(2, (ktv) + 1, smem + ABUF(((ktv) + 1) & 1));         \
              SG_A(3, (ktv) + 1, smem + ABUF(((ktv) + 1) & 1)); }       \
    BARRIER();                                                          \
    /* ph2 */                                                           \
    MFMA_P(1);                                                          \
    READ_A2(ABUF((ktv) & 1), 2);                                        \
    BARRIER();                                                          \
    /* ph3: stage B(t+2); counted wait */                               \
    MFMA_P(2);                                                          \
    READ_A2(ABUF((ktv) & 1), 3);                                        \
    if (SB) { SG_B(0, (ktv) + 2, smem + BBUF((ktv) & 1));               \
              SG_B(1, (ktv) + 2, smem + BBUF((ktv) & 1));               \
              SG_B(2, (ktv) + 2, smem + BBUF((ktv) & 1));               \
              SG_B(3, (ktv) + 2, smem + BBUF((ktv) & 1)); }             \
    if (HASW) { WAITV(WV); }                                            \
    BARRIER();                                                          \
    /* ph4: read next tile's A frags 0,1 + bfp[0..1] */                 \
    MFMA_P(3);                                                          \
    if (RDN) { READ_A2(ABUF(((ktv) + 1) & 1), 0);                       \
               READ_B2(BBUF(((ktv) + 1) & 1), 0);                       \
               READ_B2(BBUF(((ktv) + 1) & 1), 1); }                     \
    BARRIER();                                                          \
  }

__global__ __launch_bounds__(512, 1) void kgemm3(const unsigned char* __restrict__ reps8,
                                                 float* __restrict__ partial) {
  extern __shared__ char smem[];

  // XCD-aware swizzle (512 = 8 * 64, bijective), then decode into the
  // 512-tile list: triangle minus tiles (0, 16..31).
  int bid = (int)blockIdx.x;
  bid = (bid & 7) * 64 + (bid >> 3);
  int rb, cb;
  if (bid < 16) {
    rb = 0; cb = bid;
  } else {
    int rem = bid - 16;
    rb = 1;
    while (rem >= NTB - rb) { rem -= NTB - rb; rb++; }
    cb = rb + rem;
  }

  const int t = threadIdx.x;
  const int l = t & 63, w = t >> 6;
  const int wr = w >> 2, wc = w & 3;          // 2 x 4 wave grid

  f32x4 acc[8][4];
  const f32x4 zero4 = {0.f, 0.f, 0.f, 0.f};
#pragma unroll
  for (int m = 0; m < 8; m++)
#pragma unroll
    for (int n = 0; n < 4; n++) acc[m][n] = zero4;

  const size_t arow0 = (size_t)rb * 256;
  const size_t brow0 = (size_t)cb * 256;

  // read-side: lane q-group holds orig chunks {2q, 2q+1}; LDS pos = chunk ^ (row&7)
  const int q2 = (l >> 4) & 3;
  const int arow = wr * 128 + (l & 15);
  const int brow = wc * 64 + (l & 15);
  const int r7 = l & 7;                       // == arow&7 == brow&7
  const int aaddr0 = arow * 128 + (((2 * q2) ^ r7) << 4);
  const int aaddr1 = arow * 128 + (((2 * q2 + 1) ^ r7) << 4);
  const int baddr0 = brow * 128 + (((2 * q2) ^ r7) << 4);
  const int baddr1 = brow * 128 + (((2 * q2 + 1) ^ r7) << 4);

  // ---- prologue: B(0), A(0), B(1); retire B(0)+A(0); preload tile-0 ph1 ops ----
  SG_B(0, 0, smem + 32768); SG_B(1, 0, smem + 32768);
  SG_B(2, 0, smem + 32768); SG_B(3, 0, smem + 32768);
  SG_A(0, 0, smem); SG_A(1, 0, smem); SG_A(2, 0, smem); SG_A(3, 0, smem);
  SG_B(0, 1, smem + 49152); SG_B(1, 1, smem + 49152);
  SG_B(2, 1, smem + 49152); SG_B(3, 1, smem + 49152);
  WAITV(4);
  BARRIER();

  i32x8 afp[2], bfp[4];
  READ_A2(0, 0);
  READ_B2(32768, 0);
  READ_B2(32768, 1);

  DO_TILE(0, 1, 1, 1, 1, 4)
  DO_TILE(1, 1, 1, 1, 1, 4)
  DO_TILE(2, 1, 1, 1, 1, 4)
  DO_TILE(3, 1, 1, 1, 1, 4)
  DO_TILE(4, 1, 1, 1, 1, 4)
  DO_TILE(5, 1, 1, 1, 1, 4)
  DO_TILE(6, 1, 0, 1, 1, 0)
  DO_TILE(7, 0, 0, 0, 0, 0)

  // -------- epilogue: exp + diagonal mask + row/col partial sums --------
  float rsum[8][4];
  float csum[4];
#pragma unroll
  for (int m = 0; m < 8; m++)
#pragma unroll
    for (int j = 0; j < 4; j++) rsum[m][j] = 0.f;
#pragma unroll
  for (int n = 0; n < 4; n++) csum[n] = 0.f;

  const int col16 = l & 15, rgp = (l >> 4) & 3;
  const bool diag = (rb == cb);
  const int growbase = wr * 128 + rgp * 4;
  const int gcolbase = wc * 64 + col16;
#pragma unroll
  for (int m = 0; m < 8; m++) {
#pragma unroll
    for (int n = 0; n < 4; n++) {
#pragma unroll
      for (int j = 0; j < 4; j++) {
        const float e = (diag && (growbase + m * 16 + j) == (gcolbase + n * 16))
                            ? 0.f
                            : exp2f(acc[m][n][j] * EXPSCALE);
        rsum[m][j] += e;
        csum[n] += e;
      }
    }
  }
#pragma unroll
  for (int m = 0; m < 8; m++)
#pragma unroll
    for (int j = 0; j < 4; j++) {
      float v = rsum[m][j];
      v += __shfl_xor(v, 1); v += __shfl_xor(v, 2);
      v += __shfl_xor(v, 4); v += __shfl_xor(v, 8);
      rsum[m][j] = v;
    }
#pragma unroll
  for (int n = 0; n < 4; n++) {
    float v = csum[n];
    v += __shfl_xor(v, 16); v += __shfl_xor(v, 32);
    csum[n] = v;
  }

  float* rS = (float*)smem;            // [4 wc][256 rows]
  float* cS = ((float*)smem) + 1024;   // [2 wr][256 cols]
  if (col16 == 0) {
#pragma unroll
    for (int m = 0; m < 8; m++)
#pragma unroll
      for (int j = 0; j < 4; j++)
        rS[wc * 256 + wr * 128 + m * 16 + rgp * 4 + j] = rsum[m][j];
  }
  if (rgp == 0) {
#pragma unroll
    for (int n = 0; n < 4; n++)
      cS[wr * 256 + wc * 64 + n * 16 + col16] = csum[n];
  }
  __syncthreads();
  // partial layout: [68 col-blocks of 128][8192 rows]
  if (t < 256) {
    const float rs_lo = rS[t] + rS[256 + t];
    const float rs_hi = rS[512 + t] + rS[768 + t];
    partial[(size_t)(cb * 2) * N2 + rb * 256 + t] = rs_lo;
    partial[(size_t)(cb * 2 + 1) * N2 + rb * 256 + t] = rs_hi;
    if (!diag) {
      partial[(size_t)(rb * 2) * N2 + cb * 256 + t] = cS[t];
      partial[(size_t)(rb * 2 + 1) * N2 + cb * 256 + t] = cS[256 + t];
    }
  }
}

// ---------------- Kernel Bt: tail — 128 eighth-tiles (64x128) of tiles (0,16..31) -------
// bf16, unchanged (reads the bf16 reps copy).
#define TSG_A(ii, ktv, dst) gload16(reps + (tarow0 + (ii) * 32 + tsrow) * D + (ktv) * 128 + tschk * 8, \
                                    (dst) + (size_t)((ii) * 32 + w * 4) * 128)
#define TSG_B(ii, ktv, dst) gload16(reps + (tbrow0 + (ii) * 32 + tsrow) * D + (ktv) * 128 + tschk * 8, \
                                    (dst) + (size_t)((ii) * 32 + w * 4) * 128)

#define TRD(buf, row, kk) (*(const bf16x8*)((const char*)(buf) + (row) * 256 + \
                           ((((kk) * 4 + q4) ^ ((row) & 15)) << 4)))

#define TMFMA(kk)                                                       \
  __builtin_amdgcn_s_setprio(1);                                        \
  _Pragma("unroll") for (int m2 = 0; m2 < 2; m2++)                      \
  _Pragma("unroll") for (int n = 0; n < 2; n++)                         \
    acc[m2][n] = __builtin_amdgcn_mfma_f32_16x16x32_bf16(               \
        af[m2][kk], bf[n][kk], acc[m2][n], 0, 0, 0);                    \
  __builtin_amdgcn_s_setprio(0);

#define TTILE(tv, S, R, HASW, WV)                                       \
  {                                                                     \
    const int cur = (tv) & 1;                                           \
    const char* bA  = cur ? (const char*)tA1 : (const char*)tA0;        \
    const char* bB  = cur ? (const char*)tB1 : (const char*)tB0;        \
    const char* bAn = cur ? (const char*)tA0 : (const char*)tA1;        \
    const char* bBn = cur ? (const char*)tB0 : (const char*)tB1;        \
    short* stA = cur ? tA1 : tA0;   /* = bA buffer: parity(t+2) */      \
    short* stB = cur ? tB1 : tB0;                                       \
    _Pragma("unroll") for (int kk = 2; kk < 4; kk++) {                  \
      _Pragma("unroll") for (int m2 = 0; m2 < 2; m2++)                  \
        af[m2][kk] = TRD(bA, tarow_r + m2 * 16, kk);                    \
      _Pragma("unroll") for (int n = 0; n < 2; n++)                     \
        bf[n][kk] = TRD(bB, tbrow_r + n * 16, kk);                      \
    }                                                                   \
    TMFMA(0); TMFMA(1);                                                 \
    LGKM0();                                                            \
    BARRIER();                                                          \
    if (S) { TSG_A(0, (tv) + 2, stA); TSG_A(1, (tv) + 2, stA);          \
             TSG_B(0, (tv) + 2, stB); TSG_B(1, (tv) + 2, stB);          \
             TSG_B(2, (tv) + 2, stB); TSG_B(3, (tv) + 2, stB); }        \
    TMFMA(2); TMFMA(3);                                                 \
    if (HASW) { WAITV(WV); }                                            \
    BARRIER();                                                          \
    if (R) {                                                            \
      _Pragma("unroll") for (int kk = 0; kk < 2; kk++) {                \
        _Pragma("unroll") for (int m2 = 0; m2 < 2; m2++)                \
          af[m2][kk] = TRD(bAn, tarow_r + m2 * 16, kk);                 \
        _Pragma("unroll") for (int n = 0; n < 2; n++)                   \
          bf[n][kk] = TRD(bBn, tbrow_r + n * 16, kk);                   \
      }                                                                 \
    }                                                                   \
  }

__global__ __launch_bounds__(512) void kgemmt(const short* __restrict__ reps,
                                              float* __restrict__ partial) {
  extern __shared__ char smem[];
  short* tA0 = (short*)smem;                  // 16 KB [64][128]
  short* tA1 = (short*)(smem + 16384);
  short* tB0 = (short*)(smem + 32768);        // 32 KB [128][128]
  short* tB1 = (short*)(smem + 65536);

  const int b = (int)blockIdx.x;              // 0..127
  const int s = b >> 3, sub = b & 7;
  const int qr = sub >> 1;                    // 64-row chunk of rows 0..255
  const int qc = sub & 1;                     // 128-col half of the 256-col tile
  const int cbt = 16 + s;

  const int t = threadIdx.x;
  const int l = t & 63, w = t >> 6;
  const int wr = w >> 2, wc = w & 3;          // 2 x 4 wave grid

  f32x4 acc[2][2];
  const f32x4 zero4 = {0.f, 0.f, 0.f, 0.f};
#pragma unroll
  for (int m = 0; m < 2; m++)
#pragma unroll
    for (int n = 0; n < 2; n++) acc[m][n] = zero4;

  const int tsrow = w * 4 + (l >> 4);          // row within 32-row inst chunk
  const int tschk = (l & 15) ^ (tsrow & 15);   // pre-swizzled source 16B chunk
  const size_t tarow0 = (size_t)qr * 64;
  const size_t tbrow0 = (size_t)cbt * 256 + (size_t)qc * 128;

  const int q4 = (l >> 4) & 3;
  const int tarow_r = wr * 32 + (l & 15);
  const int tbrow_r = wc * 32 + (l & 15);

  TSG_A(0, 0, tA0); TSG_A(1, 0, tA0);
  TSG_B(0, 0, tB0); TSG_B(1, 0, tB0); TSG_B(2, 0, tB0); TSG_B(3, 0, tB0);
  TSG_A(0, 1, tA1); TSG_A(1, 1, tA1);
  TSG_B(0, 1, tB1); TSG_B(1, 1, tB1); TSG_B(2, 1, tB1); TSG_B(3, 1, tB1);
  WAITV(6);
  BARRIER();

  bf16x8 af[2][4], bf[2][4];
#pragma unroll
  for (int kk = 0; kk < 2; kk++) {
#pragma unroll
    for (int m2 = 0; m2 < 2; m2++) af[m2][kk] = TRD((const char*)tA0, tarow_r + m2 * 16, kk);
#pragma unroll
    for (int n = 0; n < 2; n++) bf[n][kk] = TRD((const char*)tB0, tbrow_r + n * 16, kk);
  }

#pragma unroll 1
  for (int tv = 0; tv < 6; ++tv) TTILE(tv, 1, 1, 1, 6)
  TTILE(6, 0, 1, 1, 0)
  TTILE(7, 0, 0, 0, 0)

  float rsum[2][4];
  float csum[2];
#pragma unroll
  for (int m = 0; m < 2; m++)
#pragma unroll
    for (int j = 0; j < 4; j++) rsum[m][j] = 0.f;
  csum[0] = 0.f; csum[1] = 0.f;

#pragma unroll
  for (int m = 0; m < 2; m++)
#pragma unroll
    for (int n = 0; n < 2; n++)
#pragma unroll
      for (int j = 0; j < 4; j++) {
        const float e = exp2f(acc[m][n][j] * EXPSCALE);
        rsum[m][j] += e;
        csum[n] += e;
      }
#pragma unroll
  for (int m = 0; m < 2; m++)
#pragma unroll
    for (int j = 0; j < 4; j++) {
      float v = rsum[m][j];
      v += __shfl_xor(v, 1); v += __shfl_xor(v, 2);
      v += __shfl_xor(v, 4); v += __shfl_xor(v, 8);
      rsum[m][j] = v;
    }
#pragma unroll
  for (int n = 0; n < 2; n++) {
    float v = csum[n];
    v += __shfl_xor(v, 16); v += __shfl_xor(v, 32);
    csum[n] = v;
  }

  const int col16 = l & 15, rgp = (l >> 4) & 3;
  float* rS = (float*)smem;            // [4 wc][64 rows]
  float* cS = ((float*)smem) + 256;    // [2 wr][128 cols]
  if (col16 == 0) {
#pragma unroll
    for (int m = 0; m < 2; m++)
#pragma unroll
      for (int j = 0; j < 4; j++)
        rS[wc * 64 + wr * 32 + m * 16 + rgp * 4 + j] = rsum[m][j];
  }
  if (rgp == 0) {
#pragma unroll
    for (int n = 0; n < 2; n++)
      cS[wr * 128 + wc * 32 + n * 16 + col16] = csum[n];
  }
  __syncthreads();
  if (t < 64) {
    const float rs = rS[t] + rS[64 + t] + rS[128 + t] + rS[192 + t];
    partial[(size_t)(cbt * 2 + qc) * N2 + qr * 64 + t] = rs;
  }
  if (t < 128) {
    const float cs = cS[t] + cS[128 + t];
    partial[(size_t)(64 + qr) * N2 + cbt * 256 + qc * 128 + t] = cs;
  }
}

// ---------------- Kernel C1: per-row denom; log; block sum --------------------------------
__device__ inline float blockReduce(float v, float* sred) {
#pragma unroll
  for (int o = 32; o > 0; o >>= 1) v += __shfl_xor(v, o);
  const int lane = threadIdx.x & 63, wid = threadIdx.x >> 6;
  if (lane == 0) sred[wid] = v;
  __syncthreads();
  v = sred[0] + sred[1] + sred[2] + sred[3];
  __syncthreads();
  return v;
}

__global__ __launch_bounds__(256) void kred1(const float* __restrict__ partial,
                                             float* __restrict__ bsum) {
  const int r = blockIdx.x * 256 + threadIdx.x;
  float d = 0.f;
#pragma unroll 8
  for (int cbx = 0; cbx < 64; ++cbx) d += partial[(size_t)cbx * N2 + r];
  if (blockIdx.x >= 16) {   // rows >= 4096: add tail colsum slots 64..67
#pragma unroll
    for (int cbx = 64; cbx < 68; ++cbx) d += partial[(size_t)cbx * N2 + r];
  }
  float v = logf(d);
  __shared__ float sred[4];
  v = blockReduce(v, sred);
  if (threadIdx.x == 0) bsum[blockIdx.x] = v;
}

// ---------------- Kernel C2: final scalar -------------------------------------------------
__global__ __launch_bounds__(256) void kred2(const float* __restrict__ bsum,
                                             const float* __restrict__ pos,
                                             float* __restrict__ out) {
  const int t = threadIdx.x;
  float v = (t < 32) ? bsum[t] : 0.f;
  float p = 0.f;
  for (int k = t; k < BSZ; k += 256) p += pos[k];
  __shared__ float sred[4];
  v = blockReduce(v, sred);
  p = blockReduce(p, sred);
  if (t == 0) out[0] = (v - 2.0f * p / TEMPV) / (float)N2;
}

extern "C" void kernel_launch(void* const* d_in, const int* in_sizes, int n_in,
                              void* d_out, int out_size, void* d_ws, size_t ws_size,
                              hipStream_t stream) {
  const float* ei = (const float*)d_in[0];
  const float* ej = (const float*)d_in[1];
  char* ws = (char*)d_ws;
  unsigned short* reps = (unsigned short*)ws;                          // 16 MB bf16 [8192][1024]
  unsigned char* reps8 = (unsigned char*)(ws + (size_t)16 * 1024 * 1024); // 8 MB fp8 (plain)
  float* partial = (float*)(ws + (size_t)24 * 1024 * 1024);            // 2.13 MB [68][8192]
  float* pos = (float*)(ws + (size_t)24 * 1024 * 1024 + 2304 * 1024);  // 16 KB [4096]
  float* bsum = (float*)(ws + (size_t)24 * 1024 * 1024 + 2304 * 1024 + 16384); // 128 B

  (void)hipFuncSetAttribute((const void*)kgemm3,
                            hipFuncAttributeMaxDynamicSharedMemorySize, 131072);
  (void)hipFuncSetAttribute((const void*)kgemmt,
                            hipFuncAttributeMaxDynamicSharedMemorySize, 98304);

  knorm<<<BSZ, 256, 0, stream>>>(ei, ej, reps, reps8, pos);
  kgemm3<<<512, 512, 131072, stream>>>(reps8, partial);
  kgemmt<<<128, 512, 98304, stream>>>((const short*)reps, partial);
  kred1<<<32, 256, 0, stream>>>(partial, bsum);
  kred2<<<1, 256, 0, stream>>>(bsum, pos, (float*)d_out);
}

// Round 14
// 73.516 us; speedup vs baseline: 1.1939x; 1.0163x over previous
//
#include <hip/hip_runtime.h>

#define BSZ 4096
#define D 1024
#define N2 8192
#define TEMPV 0.5f
// exp(x/T) = exp2(x * log2(e)/T)
#define EXPSCALE 2.8853900817779268f
#define NTB 32      // 8192 / 256 tiles per dim

typedef __attribute__((ext_vector_type(8))) short bf16x8;
typedef __attribute__((ext_vector_type(4))) float f32x4;
typedef __attribute__((ext_vector_type(4))) int i32x4;
typedef __attribute__((ext_vector_type(8))) int i32x8;

__device__ inline unsigned short f2bf(float x) {
  unsigned int u = __float_as_uint(x);
  u += 0x7fffu + ((u >> 16) & 1u);   // round-to-nearest-even
  return (unsigned short)(u >> 16);
}

// bit-exact float -> OCP e4m3fn, RNE (inputs |x|<=1 here; clamp kept for safety)
__device__ inline unsigned int f2e4m3(float x) {
  unsigned int u = __float_as_uint(x);
  const unsigned int s = (u >> 24) & 0x80u;
  u &= 0x7fffffffu;
  const float a = __uint_as_float(u);
  if (a >= 448.0f) return s | 0x7Eu;
  if (a < 0.015625f) {                       // < 2^-6: subnormal
    const int m = (int)rintf(a * 512.0f);    // RNE; 8 -> 0x08 == 2^-6 exactly
    return s | (unsigned int)m;
  }
  u += 0x7FFFFu + ((u >> 20) & 1u);          // RNE to 3 mantissa bits
  const unsigned int e = u >> 23;            // biased f32 exp (>=121)
  const unsigned int m3 = (u >> 20) & 7u;
  return s | (((e - 120u) << 3) | m3);       // e4m3 bias 7
}

__device__ inline void gload16(const void* g, void* l) {
  __builtin_amdgcn_global_load_lds(
      (const __attribute__((address_space(1))) void*)g,
      (__attribute__((address_space(3))) void*)l, 16, 0, 0);
}

// ---------------- Kernel A: L2-normalize rows, emit bf16 + plain fp8 reps --------------
__global__ __launch_bounds__(256) void knorm(const float* __restrict__ ei,
                                             const float* __restrict__ ej,
                                             unsigned short* __restrict__ reps,
                                             unsigned char* __restrict__ reps8,
                                             float* __restrict__ pos) {
  const int r = blockIdx.x;
  const int t = threadIdx.x;
  const float4 vi = ((const float4*)(ei + (size_t)r * D))[t];
  const float4 vj = ((const float4*)(ej + (size_t)r * D))[t];
  float ssi = vi.x * vi.x + vi.y * vi.y + vi.z * vi.z + vi.w * vi.w;
  float ssj = vj.x * vj.x + vj.y * vj.y + vj.z * vj.z + vj.w * vj.w;
  float sij = vi.x * vj.x + vi.y * vj.y + vi.z * vj.z + vi.w * vj.w;
#pragma unroll
  for (int o = 32; o > 0; o >>= 1) {
    ssi += __shfl_xor(ssi, o);
    ssj += __shfl_xor(ssj, o);
    sij += __shfl_xor(sij, o);
  }
  __shared__ float red[12];
  const int lane = t & 63, wid = t >> 6;
  if (lane == 0) { red[wid * 3] = ssi; red[wid * 3 + 1] = ssj; red[wid * 3 + 2] = sij; }
  __syncthreads();
  ssi = red[0] + red[3] + red[6] + red[9];
  ssj = red[1] + red[4] + red[7] + red[10];
  sij = red[2] + red[5] + red[8] + red[11];
  const float inv_i = rsqrtf(fmaxf(ssi, 1e-24f));
  const float inv_j = rsqrtf(fmaxf(ssj, 1e-24f));
  const float xi0 = vi.x * inv_i, xi1 = vi.y * inv_i, xi2 = vi.z * inv_i, xi3 = vi.w * inv_i;
  const float xj0 = vj.x * inv_j, xj1 = vj.y * inv_j, xj2 = vj.z * inv_j, xj3 = vj.w * inv_j;
  ushort4 ui, uj;
  ui.x = f2bf(xi0); ui.y = f2bf(xi1); ui.z = f2bf(xi2); ui.w = f2bf(xi3);
  uj.x = f2bf(xj0); uj.y = f2bf(xj1); uj.z = f2bf(xj2); uj.w = f2bf(xj3);
  *((ushort4*)(reps + (size_t)r * D) + t) = ui;
  *((ushort4*)(reps + (size_t)(BSZ + r) * D) + t) = uj;
  const unsigned int pi = f2e4m3(xi0) | (f2e4m3(xi1) << 8) | (f2e4m3(xi2) << 16) | (f2e4m3(xi3) << 24);
  const unsigned int pj = f2e4m3(xj0) | (f2e4m3(xj1) << 8) | (f2e4m3(xj2) << 16) | (f2e4m3(xj3) << 24);
  *(unsigned int*)(reps8 + (size_t)r * 1024 + t * 4) = pi;
  *(unsigned int*)(reps8 + (size_t)(BSZ + r) * 1024 + t * 4) = pj;
  if (t == 0) pos[r] = sij * inv_i * inv_j;
}

// ======================= shared asm helpers =======================
#define BARRIER() do { __builtin_amdgcn_s_barrier(); asm volatile("" ::: "memory"); } while (0)
#define STR2(x) #x
#define WAITV(n) asm volatile("s_waitcnt vmcnt(" STR2(n) ")" ::: "memory")
#define LGKM0() asm volatile("s_waitcnt lgkmcnt(0)" ::: "memory")

// ---------------- Kernel B (merged): 512 main 256x256 MX-fp8 tiles + 128 tail blocks ----
// Main path (blocks 0..511): 8 waves (2M x 4N), wave tile 128x64, BK=128 fp8.
// LDS 128 KiB: A dbuf @0/@16384(x2KB..32KB), B dbuf @32768/@49152. Fully unrolled 8
// K-tiles (compile-time parities -> 128 arch VGPR + 128 acc = exactly the 256 cap, 0 spill).
// Tail path (blocks 512..639): bf16 64x128 eighth-tiles of excluded tiles (0,16..31);
// ~T/6 per block, dispatched after the mains' 2 clean rounds -> fills straggler window.
#define SG_A(ii, ktv, dst) gload16(reps8 + (size_t)(arow0 + (ii) * 64 + (t >> 3)) * 1024 + \
                                       (ktv) * 128 + (((t & 7) ^ ((t >> 3) & 7)) << 4),    \
                                   (dst) + (size_t)(ii) * 8192 + (size_t)t * 16)
#define SG_B(ii, ktv, dst) gload16(reps8 + (size_t)(brow0 + (ii) * 64 + (t >> 3)) * 1024 + \
                                       (ktv) * 128 + (((t & 7) ^ ((t >> 3) & 7)) << 4),    \
                                   (dst) + (size_t)(ii) * 8192 + (size_t)t * 16)

#define ABUF(c) ((c) ? 16384 : 0)
#define BBUF(c) ((c) ? 49152 : 32768)

#define READ_A2(bufoff, p) do {                                                       \
    i32x4 a0l = *(const i32x4*)(smem + (bufoff) + ((p) * 2) * 2048 + aaddr0);         \
    i32x4 a0h = *(const i32x4*)(smem + (bufoff) + ((p) * 2) * 2048 + aaddr1);         \
    i32x4 a1l = *(const i32x4*)(smem + (bufoff) + ((p) * 2 + 1) * 2048 + aaddr0);     \
    i32x4 a1h = *(const i32x4*)(smem + (bufoff) + ((p) * 2 + 1) * 2048 + aaddr1);     \
    afp[0] = __builtin_shufflevector(a0l, a0h, 0, 1, 2, 3, 4, 5, 6, 7);               \
    afp[1] = __builtin_shufflevector(a1l, a1h, 0, 1, 2, 3, 4, 5, 6, 7);               \
  } while (0)

#define READ_B2(bufoff, n) do {                                                       \
    i32x4 bl = *(const i32x4*)(smem + (bufoff) + (n) * 2048 + baddr0);                \
    i32x4 bh = *(const i32x4*)(smem + (bufoff) + (n) * 2048 + baddr1);                \
    bfp[n] = __builtin_shufflevector(bl, bh, 0, 1, 2, 3, 4, 5, 6, 7);                 \
  } while (0)

#define MFMA_P(p)                                                       \
  __builtin_amdgcn_s_setprio(1);                                        \
  _Pragma("unroll") for (int nh = 0; nh < 2; nh++)                      \
  _Pragma("unroll") for (int m2 = 0; m2 < 2; m2++)                      \
  _Pragma("unroll") for (int nn = 0; nn < 2; nn++) {                    \
    const int n_ = nh * 2 + nn;                                         \
    acc[2 * (p) + m2][n_] = __builtin_amdgcn_mfma_scale_f32_16x16x128_f8f6f4( \
        afp[m2], bfp[n_], acc[2 * (p) + m2][n_],                        \
        0, 0, 0, 0x7F7F7F7F, 0, 0x7F7F7F7F);                            \
  }                                                                     \
  __builtin_amdgcn_s_setprio(0);

#define DO_TILE(ktv, SA, SB, RDN, HASW, WV)                             \
  {                                                                     \
    READ_B2(BBUF((ktv) & 1), 2); READ_B2(BBUF((ktv) & 1), 3);           \
    MFMA_P(0);                                                          \
    READ_A2(ABUF((ktv) & 1), 1);                                        \
    if (SA) { SG_A(0, (ktv) + 1, smem + ABUF(((ktv) + 1) & 1));         \
              SG_A(1, (ktv) + 1, smem + ABUF(((ktv) + 1) & 1));         \
              SG_A(2, (ktv) + 1, smem + ABUF(((ktv) + 1) & 1));         \
              SG_A(3, (ktv) + 1, smem + ABUF(((ktv) + 1) & 1)); }       \
    BARRIER();                                                          \
    MFMA_P(1);                                                          \
    READ_A2(ABUF((ktv) & 1), 2);                                        \
    BARRIER();                                                          \
    MFMA_P(2);                                                          \
    READ_A2(ABUF((ktv) & 1), 3);                                        \
    if (SB) { SG_B(0, (ktv) + 2, smem + BBUF((ktv) & 1));               \
              SG_B(1, (ktv) + 2, smem + BBUF((ktv) & 1));               \
              SG_B(2, (ktv) + 2, smem + BBUF((ktv) & 1));               \
              SG_B(3, (ktv) + 2, smem + BBUF((ktv) & 1)); }             \
    if (HASW) { WAITV(WV); }                                            \
    BARRIER();                                                          \
    MFMA_P(3);                                                          \
    if (RDN) { READ_A2(ABUF(((ktv) + 1) & 1), 0);                       \
               READ_B2(BBUF(((ktv) + 1) & 1), 0);                       \
               READ_B2(BBUF(((ktv) + 1) & 1), 1); }                     \
    BARRIER();                                                          \
  }

// -------- tail-path macros (bf16 engine, reads the bf16 reps copy) --------
#define TSG_A(ii, ktv, dst) gload16(reps + (tarow0 + (ii) * 32 + tsrow) * D + (ktv) * 128 + tschk * 8, \
                                    (dst) + (size_t)((ii) * 32 + w * 4) * 128)
#define TSG_B(ii, ktv, dst) gload16(reps + (tbrow0 + (ii) * 32 + tsrow) * D + (ktv) * 128 + tschk * 8, \
                                    (dst) + (size_t)((ii) * 32 + w * 4) * 128)

#define TRD(buf, row, kk) (*(const bf16x8*)((const char*)(buf) + (row) * 256 + \
                           ((((kk) * 4 + q4) ^ ((row) & 15)) << 4)))

#define TMFMA(kk)                                                       \
  __builtin_amdgcn_s_setprio(1);                                        \
  _Pragma("unroll") for (int m2 = 0; m2 < 2; m2++)                      \
  _Pragma("unroll") for (int n = 0; n < 2; n++)                         \
    tacc[m2][n] = __builtin_amdgcn_mfma_f32_16x16x32_bf16(              \
        af[m2][kk], bf[n][kk], tacc[m2][n], 0, 0, 0);                   \
  __builtin_amdgcn_s_setprio(0);

#define TTILE(tv, S, R, HASW, WV)                                       \
  {                                                                     \
    const int cur = (tv) & 1;                                           \
    const char* bA  = cur ? (const char*)tA1 : (const char*)tA0;        \
    const char* bB  = cur ? (const char*)tB1 : (const char*)tB0;        \
    const char* bAn = cur ? (const char*)tA0 : (const char*)tA1;        \
    const char* bBn = cur ? (const char*)tB0 : (const char*)tB1;        \
    short* stA = cur ? tA1 : tA0;   /* = bA buffer: parity(t+2) */      \
    short* stB = cur ? tB1 : tB0;                                       \
    _Pragma("unroll") for (int kk = 2; kk < 4; kk++) {                  \
      _Pragma("unroll") for (int m2 = 0; m2 < 2; m2++)                  \
        af[m2][kk] = TRD(bA, tarow_r + m2 * 16, kk);                    \
      _Pragma("unroll") for (int n = 0; n < 2; n++)                     \
        bf[n][kk] = TRD(bB, tbrow_r + n * 16, kk);                      \
    }                                                                   \
    TMFMA(0); TMFMA(1);                                                 \
    LGKM0();                                                            \
    BARRIER();                                                          \
    if (S) { TSG_A(0, (tv) + 2, stA); TSG_A(1, (tv) + 2, stA);          \
             TSG_B(0, (tv) + 2, stB); TSG_B(1, (tv) + 2, stB);          \
             TSG_B(2, (tv) + 2, stB); TSG_B(3, (tv) + 2, stB); }        \
    TMFMA(2); TMFMA(3);                                                 \
    if (HASW) { WAITV(WV); }                                            \
    BARRIER();                                                          \
    if (R) {                                                            \
      _Pragma("unroll") for (int kk = 0; kk < 2; kk++) {                \
        _Pragma("unroll") for (int m2 = 0; m2 < 2; m2++)                \
          af[m2][kk] = TRD(bAn, tarow_r + m2 * 16, kk);                 \
        _Pragma("unroll") for (int n = 0; n < 2; n++)                   \
          bf[n][kk] = TRD(bBn, tbrow_r + n * 16, kk);                   \
      }                                                                 \
    }                                                                   \
  }

__global__ __launch_bounds__(512, 1) void kgemm3(const unsigned char* __restrict__ reps8,
                                                 const short* __restrict__ reps,
                                                 float* __restrict__ partial) {
  extern __shared__ char smem[];
  const int t = threadIdx.x;
  const int l = t & 63, w = t >> 6;

  if (blockIdx.x >= 512) {
    // ================= tail path: 64x128 eighth-tiles of tiles (0,16..31) =============
    short* tA0 = (short*)smem;                  // 16 KB [64][128]
    short* tA1 = (short*)(smem + 16384);
    short* tB0 = (short*)(smem + 32768);        // 32 KB [128][128]
    short* tB1 = (short*)(smem + 65536);

    const int b = (int)blockIdx.x - 512;        // 0..127
    const int s = b >> 3, sub = b & 7;
    const int qr = sub >> 1;                    // 64-row chunk of rows 0..255
    const int qc = sub & 1;                     // 128-col half of the 256-col tile
    const int cbt = 16 + s;

    const int wr = w >> 2, wc = w & 3;          // 2 x 4 wave grid

    f32x4 tacc[2][2];
    const f32x4 zero4t = {0.f, 0.f, 0.f, 0.f};
#pragma unroll
    for (int m = 0; m < 2; m++)
#pragma unroll
      for (int n = 0; n < 2; n++) tacc[m][n] = zero4t;

    const int tsrow = w * 4 + (l >> 4);          // row within 32-row inst chunk
    const int tschk = (l & 15) ^ (tsrow & 15);   // pre-swizzled source 16B chunk
    const size_t tarow0 = (size_t)qr * 64;
    const size_t tbrow0 = (size_t)cbt * 256 + (size_t)qc * 128;

    const int q4 = (l >> 4) & 3;
    const int tarow_r = wr * 32 + (l & 15);
    const int tbrow_r = wc * 32 + (l & 15);

    TSG_A(0, 0, tA0); TSG_A(1, 0, tA0);
    TSG_B(0, 0, tB0); TSG_B(1, 0, tB0); TSG_B(2, 0, tB0); TSG_B(3, 0, tB0);
    TSG_A(0, 1, tA1); TSG_A(1, 1, tA1);
    TSG_B(0, 1, tB1); TSG_B(1, 1, tB1); TSG_B(2, 1, tB1); TSG_B(3, 1, tB1);
    WAITV(6);
    BARRIER();

    bf16x8 af[2][4], bf[2][4];
#pragma unroll
    for (int kk = 0; kk < 2; kk++) {
#pragma unroll
      for (int m2 = 0; m2 < 2; m2++) af[m2][kk] = TRD((const char*)tA0, tarow_r + m2 * 16, kk);
#pragma unroll
      for (int n = 0; n < 2; n++) bf[n][kk] = TRD((const char*)tB0, tbrow_r + n * 16, kk);
    }

#pragma unroll 1
    for (int tv = 0; tv < 6; ++tv) TTILE(tv, 1, 1, 1, 6)
    TTILE(6, 0, 1, 1, 0)
    TTILE(7, 0, 0, 0, 0)

    float rsum[2][4];
    float csum[2];
#pragma unroll
    for (int m = 0; m < 2; m++)
#pragma unroll
      for (int j = 0; j < 4; j++) rsum[m][j] = 0.f;
    csum[0] = 0.f; csum[1] = 0.f;

#pragma unroll
    for (int m = 0; m < 2; m++)
#pragma unroll
      for (int n = 0; n < 2; n++)
#pragma unroll
        for (int j = 0; j < 4; j++) {
          const float e = exp2f(tacc[m][n][j] * EXPSCALE);
          rsum[m][j] += e;
          csum[n] += e;
        }
#pragma unroll
    for (int m = 0; m < 2; m++)
#pragma unroll
      for (int j = 0; j < 4; j++) {
        float v = rsum[m][j];
        v += __shfl_xor(v, 1); v += __shfl_xor(v, 2);
        v += __shfl_xor(v, 4); v += __shfl_xor(v, 8);
        rsum[m][j] = v;
      }
#pragma unroll
    for (int n = 0; n < 2; n++) {
      float v = csum[n];
      v += __shfl_xor(v, 16); v += __shfl_xor(v, 32);
      csum[n] = v;
    }

    const int col16 = l & 15, rgp = (l >> 4) & 3;
    float* rS = (float*)smem;            // [4 wc][64 rows]
    float* cS = ((float*)smem) + 256;    // [2 wr][128 cols]
    if (col16 == 0) {
#pragma unroll
      for (int m = 0; m < 2; m++)
#pragma unroll
        for (int j = 0; j < 4; j++)
          rS[wc * 64 + wr * 32 + m * 16 + rgp * 4 + j] = rsum[m][j];
    }
    if (rgp == 0) {
#pragma unroll
      for (int n = 0; n < 2; n++)
        cS[wr * 128 + wc * 32 + n * 16 + col16] = csum[n];
    }
    __syncthreads();
    if (t < 64) {
      const float rs = rS[t] + rS[64 + t] + rS[128 + t] + rS[192 + t];
      partial[(size_t)(cbt * 2 + qc) * N2 + qr * 64 + t] = rs;
    }
    if (t < 128) {
      const float cs = cS[t] + cS[128 + t];
      partial[(size_t)(64 + qr) * N2 + cbt * 256 + qc * 128 + t] = cs;
    }
    return;
  }

  // ================= main path: 256x256 MX-fp8 tiles =================================
  // XCD-aware swizzle (512 = 8 * 64, bijective), then decode into the
  // 512-tile list: triangle minus tiles (0, 16..31).
  int bid = (int)blockIdx.x;
  bid = (bid & 7) * 64 + (bid >> 3);
  int rb, cb;
  if (bid < 16) {
    rb = 0; cb = bid;
  } else {
    int rem = bid - 16;
    rb = 1;
    while (rem >= NTB - rb) { rem -= NTB - rb; rb++; }
    cb = rb + rem;
  }

  const int wr = w >> 2, wc = w & 3;          // 2 x 4 wave grid

  f32x4 acc[8][4];
  const f32x4 zero4 = {0.f, 0.f, 0.f, 0.f};
#pragma unroll
  for (int m = 0; m < 8; m++)
#pragma unroll
    for (int n = 0; n < 4; n++) acc[m][n] = zero4;

  const size_t arow0 = (size_t)rb * 256;
  const size_t brow0 = (size_t)cb * 256;

  // read-side: lane q-group holds orig chunks {2q, 2q+1}; LDS pos = chunk ^ (row&7)
  const int q2 = (l >> 4) & 3;
  const int arow = wr * 128 + (l & 15);
  const int brow = wc * 64 + (l & 15);
  const int r7 = l & 7;                       // == arow&7 == brow&7
  const int aaddr0 = arow * 128 + (((2 * q2) ^ r7) << 4);
  const int aaddr1 = arow * 128 + (((2 * q2 + 1) ^ r7) << 4);
  const int baddr0 = brow * 128 + (((2 * q2) ^ r7) << 4);
  const int baddr1 = brow * 128 + (((2 * q2 + 1) ^ r7) << 4);

  // ---- prologue: B(0), A(0), B(1); retire B(0)+A(0); preload tile-0 ph1 ops ----
  SG_B(0, 0, smem + 32768); SG_B(1, 0, smem + 32768);
  SG_B(2, 0, smem + 32768); SG_B(3, 0, smem + 32768);
  SG_A(0, 0, smem); SG_A(1, 0, smem); SG_A(2, 0, smem); SG_A(3, 0, smem);
  SG_B(0, 1, smem + 49152); SG_B(1, 1, smem + 49152);
  SG_B(2, 1, smem + 49152); SG_B(3, 1, smem + 49152);
  WAITV(4);
  BARRIER();

  i32x8 afp[2], bfp[4];
  READ_A2(0, 0);
  READ_B2(32768, 0);
  READ_B2(32768, 1);

  DO_TILE(0, 1, 1, 1, 1, 4)
  DO_TILE(1, 1, 1, 1, 1, 4)
  DO_TILE(2, 1, 1, 1, 1, 4)
  DO_TILE(3, 1, 1, 1, 1, 4)
  DO_TILE(4, 1, 1, 1, 1, 4)
  DO_TILE(5, 1, 1, 1, 1, 4)
  DO_TILE(6, 1, 0, 1, 1, 0)
  DO_TILE(7, 0, 0, 0, 0, 0)

  // -------- epilogue: exp + diagonal mask + row/col partial sums --------
  float rsum[8][4];
  float csum[4];
#pragma unroll
  for (int m = 0; m < 8; m++)
#pragma unroll
    for (int j = 0; j < 4; j++) rsum[m][j] = 0.f;
#pragma unroll
  for (int n = 0; n < 4; n++) csum[n] = 0.f;

  const int col16 = l & 15, rgp = (l >> 4) & 3;
  const bool diag = (rb == cb);
  const int growbase = wr * 128 + rgp * 4;
  const int gcolbase = wc * 64 + col16;
#pragma unroll
  for (int m = 0; m < 8; m++) {
#pragma unroll
    for (int n = 0; n < 4; n++) {
#pragma unroll
      for (int j = 0; j < 4; j++) {
        const float e = (diag && (growbase + m * 16 + j) == (gcolbase + n * 16))
                            ? 0.f
                            : exp2f(acc[m][n][j] * EXPSCALE);
        rsum[m][j] += e;
        csum[n] += e;
      }
    }
  }
#pragma unroll
  for (int m = 0; m < 8; m++)
#pragma unroll
    for (int j = 0; j < 4; j++) {
      float v = rsum[m][j];
      v += __shfl_xor(v, 1); v += __shfl_xor(v, 2);
      v += __shfl_xor(v, 4); v += __shfl_xor(v, 8);
      rsum[m][j] = v;
    }
#pragma unroll
  for (int n = 0; n < 4; n++) {
    float v = csum[n];
    v += __shfl_xor(v, 16); v += __shfl_xor(v, 32);
    csum[n] = v;
  }

  float* rS = (float*)smem;            // [4 wc][256 rows]
  float* cS = ((float*)smem) + 1024;   // [2 wr][256 cols]
  if (col16 == 0) {
#pragma unroll
    for (int m = 0; m < 8; m++)
#pragma unroll
      for (int j = 0; j < 4; j++)
        rS[wc * 256 + wr * 128 + m * 16 + rgp * 4 + j] = rsum[m][j];
  }
  if (rgp == 0) {
#pragma unroll
    for (int n = 0; n < 4; n++)
      cS[wr * 256 + wc * 64 + n * 16 + col16] = csum[n];
  }
  __syncthreads();
  // partial layout: [68 col-blocks of 128][8192 rows]
  if (t < 256) {
    const float rs_lo = rS[t] + rS[256 + t];
    const float rs_hi = rS[512 + t] + rS[768 + t];
    partial[(size_t)(cb * 2) * N2 + rb * 256 + t] = rs_lo;
    partial[(size_t)(cb * 2 + 1) * N2 + rb * 256 + t] = rs_hi;
    if (!diag) {
      partial[(size_t)(rb * 2) * N2 + cb * 256 + t] = cS[t];
      partial[(size_t)(rb * 2 + 1) * N2 + cb * 256 + t] = cS[256 + t];
    }
  }
}

// ---------------- Kernel C1: per-row denom; log; block sum --------------------------------
__device__ inline float blockReduce(float v, float* sred) {
#pragma unroll
  for (int o = 32; o > 0; o >>= 1) v += __shfl_xor(v, o);
  const int lane = threadIdx.x & 63, wid = threadIdx.x >> 6;
  if (lane == 0) sred[wid] = v;
  __syncthreads();
  v = sred[0] + sred[1] + sred[2] + sred[3];
  __syncthreads();
  return v;
}

__global__ __launch_bounds__(256) void kred1(const float* __restrict__ partial,
                                             float* __restrict__ bsum) {
  const int r = blockIdx.x * 256 + threadIdx.x;
  float d = 0.f;
#pragma unroll 8
  for (int cbx = 0; cbx < 64; ++cbx) d += partial[(size_t)cbx * N2 + r];
  if (blockIdx.x >= 16) {   // rows >= 4096: add tail colsum slots 64..67
#pragma unroll
    for (int cbx = 64; cbx < 68; ++cbx) d += partial[(size_t)cbx * N2 + r];
  }
  float v = logf(d);
  __shared__ float sred[4];
  v = blockReduce(v, sred);
  if (threadIdx.x == 0) bsum[blockIdx.x] = v;
}

// ---------------- Kernel C2: final scalar -------------------------------------------------
__global__ __launch_bounds__(256) void kred2(const float* __restrict__ bsum,
                                             const float* __restrict__ pos,
                                             float* __restrict__ out) {
  const int t = threadIdx.x;
  float v = (t < 32) ? bsum[t] : 0.f;
  float p = 0.f;
  for (int k = t; k < BSZ; k += 256) p += pos[k];
  __shared__ float sred[4];
  v = blockReduce(v, sred);
  p = blockReduce(p, sred);
  if (t == 0) out[0] = (v - 2.0f * p / TEMPV) / (float)N2;
}

extern "C" void kernel_launch(void* const* d_in, const int* in_sizes, int n_in,
                              void* d_out, int out_size, void* d_ws, size_t ws_size,
                              hipStream_t stream) {
  const float* ei = (const float*)d_in[0];
  const float* ej = (const float*)d_in[1];
  char* ws = (char*)d_ws;
  unsigned short* reps = (unsigned short*)ws;                          // 16 MB bf16 [8192][1024]
  unsigned char* reps8 = (unsigned char*)(ws + (size_t)16 * 1024 * 1024); // 8 MB fp8 (plain)
  float* partial = (float*)(ws + (size_t)24 * 1024 * 1024);            // 2.13 MB [68][8192]
  float* pos = (float*)(ws + (size_t)24 * 1024 * 1024 + 2304 * 1024);  // 16 KB [4096]
  float* bsum = (float*)(ws + (size_t)24 * 1024 * 1024 + 2304 * 1024 + 16384); // 128 B

  (void)hipFuncSetAttribute((const void*)kgemm3,
                            hipFuncAttributeMaxDynamicSharedMemorySize, 131072);

  knorm<<<BSZ, 256, 0, stream>>>(ei, ej, reps, reps8, pos);
  kgemm3<<<640, 512, 131072, stream>>>(reps8, (const short*)reps, partial);
  kred1<<<32, 256, 0, stream>>>(partial, bsum);
  kred2<<<1, 256, 0, stream>>>(bsum, pos, (float*)d_out);
}

// Round 15
// 67.127 us; speedup vs baseline: 1.3075x; 1.0952x over previous
//
#include <hip/hip_runtime.h>

#define BSZ 4096
#define D 1024
#define N2 8192
#define TEMPV 0.5f
// exp(x/T) = exp2(x * log2(e)/T)
#define EXPSCALE 2.8853900817779268f
#define NTB 32      // 8192 / 256 tiles per dim

typedef __attribute__((ext_vector_type(4))) float f32x4;
typedef __attribute__((ext_vector_type(4))) int i32x4;
typedef __attribute__((ext_vector_type(8))) int i32x8;

// bit-exact float -> OCP e4m3fn, RNE (inputs |x|<=1 here; clamp kept for safety)
__device__ inline unsigned int f2e4m3(float x) {
  unsigned int u = __float_as_uint(x);
  const unsigned int s = (u >> 24) & 0x80u;
  u &= 0x7fffffffu;
  const float a = __uint_as_float(u);
  if (a >= 448.0f) return s | 0x7Eu;
  if (a < 0.015625f) {                       // < 2^-6: subnormal
    const int m = (int)rintf(a * 512.0f);    // RNE; 8 -> 0x08 == 2^-6 exactly
    return s | (unsigned int)m;
  }
  u += 0x7FFFFu + ((u >> 20) & 1u);          // RNE to 3 mantissa bits
  const unsigned int e = u >> 23;            // biased f32 exp (>=121)
  const unsigned int m3 = (u >> 20) & 7u;
  return s | (((e - 120u) << 3) | m3);       // e4m3 bias 7
}

__device__ inline void gload16(const void* g, void* l) {
  __builtin_amdgcn_global_load_lds(
      (const __attribute__((address_space(1))) void*)g,
      (__attribute__((address_space(3))) void*)l, 16, 0, 0);
}

// ---------------- Kernel A: L2-normalize rows, emit fp8 reps + pos dot ------------------
__global__ __launch_bounds__(256) void knorm(const float* __restrict__ ei,
                                             const float* __restrict__ ej,
                                             unsigned char* __restrict__ reps8,
                                             float* __restrict__ pos) {
  const int r = blockIdx.x;
  const int t = threadIdx.x;
  const float4 vi = ((const float4*)(ei + (size_t)r * D))[t];
  const float4 vj = ((const float4*)(ej + (size_t)r * D))[t];
  float ssi = vi.x * vi.x + vi.y * vi.y + vi.z * vi.z + vi.w * vi.w;
  float ssj = vj.x * vj.x + vj.y * vj.y + vj.z * vj.z + vj.w * vj.w;
  float sij = vi.x * vj.x + vi.y * vj.y + vi.z * vj.z + vi.w * vj.w;
#pragma unroll
  for (int o = 32; o > 0; o >>= 1) {
    ssi += __shfl_xor(ssi, o);
    ssj += __shfl_xor(ssj, o);
    sij += __shfl_xor(sij, o);
  }
  __shared__ float red[12];
  const int lane = t & 63, wid = t >> 6;
  if (lane == 0) { red[wid * 3] = ssi; red[wid * 3 + 1] = ssj; red[wid * 3 + 2] = sij; }
  __syncthreads();
  ssi = red[0] + red[3] + red[6] + red[9];
  ssj = red[1] + red[4] + red[7] + red[10];
  sij = red[2] + red[5] + red[8] + red[11];
  const float inv_i = rsqrtf(fmaxf(ssi, 1e-24f));
  const float inv_j = rsqrtf(fmaxf(ssj, 1e-24f));
  const float xi0 = vi.x * inv_i, xi1 = vi.y * inv_i, xi2 = vi.z * inv_i, xi3 = vi.w * inv_i;
  const float xj0 = vj.x * inv_j, xj1 = vj.y * inv_j, xj2 = vj.z * inv_j, xj3 = vj.w * inv_j;
  const unsigned int pi = f2e4m3(xi0) | (f2e4m3(xi1) << 8) | (f2e4m3(xi2) << 16) | (f2e4m3(xi3) << 24);
  const unsigned int pj = f2e4m3(xj0) | (f2e4m3(xj1) << 8) | (f2e4m3(xj2) << 16) | (f2e4m3(xj3) << 24);
  *(unsigned int*)(reps8 + (size_t)r * 1024 + t * 4) = pi;
  *(unsigned int*)(reps8 + (size_t)(BSZ + r) * 1024 + t * 4) = pj;
  if (t == 0) pos[r] = sij * inv_i * inv_j;
}

// ======================= shared asm helpers =======================
#define BARRIER() do { __builtin_amdgcn_s_barrier(); asm volatile("" ::: "memory"); } while (0)
#define STR2(x) #x
#define WAITV(n) asm volatile("s_waitcnt vmcnt(" STR2(n) ")" ::: "memory")
#define LGKM0() asm volatile("s_waitcnt lgkmcnt(0)" ::: "memory")

// ---------------- Kernel B (merged): tails FIRST (0..127), mains (128..639) -------------
// Main: 256x256 MX-fp8 tile (unit scales), BK=128, 8 waves (2Mx4N), wave tile 128x64,
// LDS 128 KiB (A dbuf @0/@16384, B dbuf @32768/@49152), fully unrolled 8 K-tiles.
// Tail: 64x128 eighth-tiles of excluded tiles (0,16..31), same MX engine, 32x32 wave
// tiles, LDS 48 KiB (A dbuf @0/@8192, B dbuf @16384/@32768), lgkm-drained turnover.
// Tails are ~1/6 of a main and co-dispatch with round-1 mains -> pure backfill.
#define SG_A(ii, ktv, dst) gload16(reps8 + (size_t)(arow0 + (ii) * 64 + (t >> 3)) * 1024 + \
                                       (ktv) * 128 + (((t & 7) ^ ((t >> 3) & 7)) << 4),    \
                                   (dst) + (size_t)(ii) * 8192 + (size_t)t * 16)
#define SG_B(ii, ktv, dst) gload16(reps8 + (size_t)(brow0 + (ii) * 64 + (t >> 3)) * 1024 + \
                                       (ktv) * 128 + (((t & 7) ^ ((t >> 3) & 7)) << 4),    \
                                   (dst) + (size_t)(ii) * 8192 + (size_t)t * 16)

#define ABUF(c) ((c) ? 16384 : 0)
#define BBUF(c) ((c) ? 49152 : 32768)

#define READ_A2(bufoff, p) do {                                                       \
    i32x4 a0l = *(const i32x4*)(smem + (bufoff) + ((p) * 2) * 2048 + aaddr0);         \
    i32x4 a0h = *(const i32x4*)(smem + (bufoff) + ((p) * 2) * 2048 + aaddr1);         \
    i32x4 a1l = *(const i32x4*)(smem + (bufoff) + ((p) * 2 + 1) * 2048 + aaddr0);     \
    i32x4 a1h = *(const i32x4*)(smem + (bufoff) + ((p) * 2 + 1) * 2048 + aaddr1);     \
    afp[0] = __builtin_shufflevector(a0l, a0h, 0, 1, 2, 3, 4, 5, 6, 7);               \
    afp[1] = __builtin_shufflevector(a1l, a1h, 0, 1, 2, 3, 4, 5, 6, 7);               \
  } while (0)

#define READ_B2(bufoff, n) do {                                                       \
    i32x4 bl = *(const i32x4*)(smem + (bufoff) + (n) * 2048 + baddr0);                \
    i32x4 bh = *(const i32x4*)(smem + (bufoff) + (n) * 2048 + baddr1);                \
    bfp[n] = __builtin_shufflevector(bl, bh, 0, 1, 2, 3, 4, 5, 6, 7);                 \
  } while (0)

#define MFMA_P(p)                                                       \
  __builtin_amdgcn_s_setprio(1);                                        \
  _Pragma("unroll") for (int nh = 0; nh < 2; nh++)                      \
  _Pragma("unroll") for (int m2 = 0; m2 < 2; m2++)                      \
  _Pragma("unroll") for (int nn = 0; nn < 2; nn++) {                    \
    const int n_ = nh * 2 + nn;                                         \
    acc[2 * (p) + m2][n_] = __builtin_amdgcn_mfma_scale_f32_16x16x128_f8f6f4( \
        afp[m2], bfp[n_], acc[2 * (p) + m2][n_],                        \
        0, 0, 0, 0x7F7F7F7F, 0, 0x7F7F7F7F);                            \
  }                                                                     \
  __builtin_amdgcn_s_setprio(0);

#define DO_TILE(ktv, SA, SB, RDN, HASW, WV)                             \
  {                                                                     \
    READ_B2(BBUF((ktv) & 1), 2); READ_B2(BBUF((ktv) & 1), 3);           \
    MFMA_P(0);                                                          \
    READ_A2(ABUF((ktv) & 1), 1);                                        \
    if (SA) { SG_A(0, (ktv) + 1, smem + ABUF(((ktv) + 1) & 1));         \
              SG_A(1, (ktv) + 1, smem + ABUF(((ktv) + 1) & 1));         \
              SG_A(2, (ktv) + 1, smem + ABUF(((ktv) + 1) & 1));         \
              SG_A(3, (ktv) + 1, smem + ABUF(((ktv) + 1) & 1)); }       \
    BARRIER();                                                          \
    MFMA_P(1);                                                          \
    READ_A2(ABUF((ktv) & 1), 2);                                        \
    BARRIER();                                                          \
    MFMA_P(2);                                                          \
    READ_A2(ABUF((ktv) & 1), 3);                                        \
    if (SB) { SG_B(0, (ktv) + 2, smem + BBUF((ktv) & 1));               \
              SG_B(1, (ktv) + 2, smem + BBUF((ktv) & 1));               \
              SG_B(2, (ktv) + 2, smem + BBUF((ktv) & 1));               \
              SG_B(3, (ktv) + 2, smem + BBUF((ktv) & 1)); }             \
    if (HASW) { WAITV(WV); }                                            \
    BARRIER();                                                          \
    MFMA_P(3);                                                          \
    if (RDN) { READ_A2(ABUF(((ktv) + 1) & 1), 0);                       \
               READ_B2(BBUF(((ktv) + 1) & 1), 0);                       \
               READ_B2(BBUF(((ktv) + 1) & 1), 1); }                     \
    BARRIER();                                                          \
  }

// -------- tail-path macros (MX-fp8, 64x128 tile, BK=128) --------
#define UABUF(c) ((c) ? 8192 : 0)
#define UBBUF(c) ((c) ? 32768 : 16384)

#define USG_A(ktv, dstoff) gload16(reps8 + (size_t)(uarow0 + (t >> 3)) * 1024 + \
                                       (ktv) * 128 + (((t & 7) ^ ((t >> 3) & 7)) << 4), \
                                   smem + (dstoff) + (size_t)t * 16)
#define USG_B(ii, ktv, dstoff) gload16(reps8 + (size_t)(ubrow0 + (ii) * 64 + (t >> 3)) * 1024 + \
                                       (ktv) * 128 + (((t & 7) ^ ((t >> 3) & 7)) << 4), \
                                   smem + (dstoff) + (size_t)(ii) * 8192 + (size_t)t * 16)

#define UREAD_A(bufoff) do {                                                          \
    i32x4 a0l = *(const i32x4*)(smem + (bufoff) + uarow * 128 + off0);                \
    i32x4 a0h = *(const i32x4*)(smem + (bufoff) + uarow * 128 + off1);                \
    i32x4 a1l = *(const i32x4*)(smem + (bufoff) + (uarow + 16) * 128 + off0);         \
    i32x4 a1h = *(const i32x4*)(smem + (bufoff) + (uarow + 16) * 128 + off1);         \
    ua[0] = __builtin_shufflevector(a0l, a0h, 0, 1, 2, 3, 4, 5, 6, 7);                \
    ua[1] = __builtin_shufflevector(a1l, a1h, 0, 1, 2, 3, 4, 5, 6, 7);                \
  } while (0)

#define UREAD_B(bufoff) do {                                                          \
    i32x4 b0l = *(const i32x4*)(smem + (bufoff) + ubrow * 128 + off0);                \
    i32x4 b0h = *(const i32x4*)(smem + (bufoff) + ubrow * 128 + off1);                \
    i32x4 b1l = *(const i32x4*)(smem + (bufoff) + (ubrow + 16) * 128 + off0);         \
    i32x4 b1h = *(const i32x4*)(smem + (bufoff) + (ubrow + 16) * 128 + off1);         \
    ub[0] = __builtin_shufflevector(b0l, b0h, 0, 1, 2, 3, 4, 5, 6, 7);                \
    ub[1] = __builtin_shufflevector(b1l, b1h, 0, 1, 2, 3, 4, 5, 6, 7);                \
  } while (0)

#define UMFMA(n)                                                        \
  __builtin_amdgcn_s_setprio(1);                                        \
  _Pragma("unroll") for (int m2 = 0; m2 < 2; m2++)                      \
    uacc[m2][n] = __builtin_amdgcn_mfma_scale_f32_16x16x128_f8f6f4(     \
        ua[m2], ub[n], uacc[m2][n], 0, 0, 0, 0x7F7F7F7F, 0, 0x7F7F7F7F);\
  __builtin_amdgcn_s_setprio(0);

#define UTILE(tv, S, R, HASW, WV)                                       \
  {                                                                     \
    UMFMA(0);                                                           \
    LGKM0();                                                            \
    BARRIER();                                                          \
    if (S) { USG_A((tv) + 2, UABUF((tv) & 1));                          \
             USG_B(0, (tv) + 2, UBBUF((tv) & 1));                       \
             USG_B(1, (tv) + 2, UBBUF((tv) & 1)); }                     \
    UMFMA(1);                                                           \
    if (HASW) { WAITV(WV); }                                            \
    BARRIER();                                                          \
    if (R) { UREAD_A(UABUF(((tv) + 1) & 1)); UREAD_B(UBBUF(((tv) + 1) & 1)); } \
  }

__global__ __launch_bounds__(512, 1) void kgemm3(const unsigned char* __restrict__ reps8,
                                                 float* __restrict__ partial) {
  extern __shared__ char smem[];
  const int t = threadIdx.x;
  const int l = t & 63, w = t >> 6;
  const int wr = w >> 2, wc = w & 3;          // 2 x 4 wave grid
  const int q2 = (l >> 4) & 3;
  const int r7 = l & 7;
  const int off0 = ((2 * q2) ^ r7) << 4;
  const int off1 = ((2 * q2 + 1) ^ r7) << 4;

  if (blockIdx.x < 128) {
    // ================= tail path: 64x128 eighth-tiles of tiles (0,16..31) =============
    const int b = (int)blockIdx.x;              // 0..127
    const int s = b >> 3, sub = b & 7;
    const int qr = sub >> 1;                    // 64-row chunk of rows 0..255
    const int qc = sub & 1;                     // 128-col half of the 256-col tile
    const int cbt = 16 + s;

    f32x4 uacc[2][2];
    const f32x4 zero4t = {0.f, 0.f, 0.f, 0.f};
#pragma unroll
    for (int m = 0; m < 2; m++)
#pragma unroll
      for (int n = 0; n < 2; n++) uacc[m][n] = zero4t;

    const size_t uarow0 = (size_t)qr * 64;
    const size_t ubrow0 = (size_t)cbt * 256 + (size_t)qc * 128;
    const int uarow = wr * 32 + (l & 15);
    const int ubrow = wc * 32 + (l & 15);

    // prologue: stage tiles 0,1; retire tile 0 (3 of 6); preload frags(0)
    USG_A(0, 0); USG_B(0, 0, 16384); USG_B(1, 0, 16384);
    USG_A(1, 8192); USG_B(0, 1, 32768); USG_B(1, 1, 32768);
    WAITV(3);
    BARRIER();

    i32x8 ua[2], ub[2];
    UREAD_A(0); UREAD_B(16384);

    UTILE(0, 1, 1, 1, 3)
    UTILE(1, 1, 1, 1, 3)
    UTILE(2, 1, 1, 1, 3)
    UTILE(3, 1, 1, 1, 3)
    UTILE(4, 1, 1, 1, 3)
    UTILE(5, 1, 1, 1, 3)
    UTILE(6, 0, 1, 1, 0)
    UTILE(7, 0, 0, 0, 0)

    float rsum[2][4];
    float csum[2];
#pragma unroll
    for (int m = 0; m < 2; m++)
#pragma unroll
      for (int j = 0; j < 4; j++) rsum[m][j] = 0.f;
    csum[0] = 0.f; csum[1] = 0.f;

#pragma unroll
    for (int m = 0; m < 2; m++)
#pragma unroll
      for (int n = 0; n < 2; n++)
#pragma unroll
        for (int j = 0; j < 4; j++) {
          const float e = exp2f(uacc[m][n][j] * EXPSCALE);
          rsum[m][j] += e;
          csum[n] += e;
        }
#pragma unroll
    for (int m = 0; m < 2; m++)
#pragma unroll
      for (int j = 0; j < 4; j++) {
        float v = rsum[m][j];
        v += __shfl_xor(v, 1); v += __shfl_xor(v, 2);
        v += __shfl_xor(v, 4); v += __shfl_xor(v, 8);
        rsum[m][j] = v;
      }
#pragma unroll
    for (int n = 0; n < 2; n++) {
      float v = csum[n];
      v += __shfl_xor(v, 16); v += __shfl_xor(v, 32);
      csum[n] = v;
    }

    const int col16 = l & 15, rgp = (l >> 4) & 3;
    float* rS = (float*)smem;            // [4 wc][64 rows]
    float* cS = ((float*)smem) + 256;    // [2 wr][128 cols]
    if (col16 == 0) {
#pragma unroll
      for (int m = 0; m < 2; m++)
#pragma unroll
        for (int j = 0; j < 4; j++)
          rS[wc * 64 + wr * 32 + m * 16 + rgp * 4 + j] = rsum[m][j];
    }
    if (rgp == 0) {
#pragma unroll
      for (int n = 0; n < 2; n++)
        cS[wr * 128 + wc * 32 + n * 16 + col16] = csum[n];
    }
    __syncthreads();
    if (t < 64) {
      const float rs = rS[t] + rS[64 + t] + rS[128 + t] + rS[192 + t];
      partial[(size_t)(cbt * 2 + qc) * N2 + qr * 64 + t] = rs;
    }
    if (t < 128) {
      const float cs = cS[t] + cS[128 + t];
      partial[(size_t)(64 + qr) * N2 + cbt * 256 + qc * 128 + t] = cs;
    }
    return;
  }

  // ================= main path: 256x256 MX-fp8 tiles =================================
  int bid = (int)blockIdx.x - 128;
  bid = (bid & 7) * 64 + (bid >> 3);   // XCD swizzle (512 = 8*64, bijective)
  int rb, cb;
  if (bid < 16) {
    rb = 0; cb = bid;
  } else {
    int rem = bid - 16;
    rb = 1;
    while (rem >= NTB - rb) { rem -= NTB - rb; rb++; }
    cb = rb + rem;
  }

  f32x4 acc[8][4];
  const f32x4 zero4 = {0.f, 0.f, 0.f, 0.f};
#pragma unroll
  for (int m = 0; m < 8; m++)
#pragma unroll
    for (int n = 0; n < 4; n++) acc[m][n] = zero4;

  const size_t arow0 = (size_t)rb * 256;
  const size_t brow0 = (size_t)cb * 256;

  const int arow = wr * 128 + (l & 15);
  const int brow = wc * 64 + (l & 15);
  const int aaddr0 = arow * 128 + off0;
  const int aaddr1 = arow * 128 + off1;
  const int baddr0 = brow * 128 + off0;
  const int baddr1 = brow * 128 + off1;

  // ---- prologue: B(0), A(0), B(1); retire B(0)+A(0); preload tile-0 ph1 ops ----
  SG_B(0, 0, smem + 32768); SG_B(1, 0, smem + 32768);
  SG_B(2, 0, smem + 32768); SG_B(3, 0, smem + 32768);
  SG_A(0, 0, smem); SG_A(1, 0, smem); SG_A(2, 0, smem); SG_A(3, 0, smem);
  SG_B(0, 1, smem + 49152); SG_B(1, 1, smem + 49152);
  SG_B(2, 1, smem + 49152); SG_B(3, 1, smem + 49152);
  WAITV(4);
  BARRIER();

  i32x8 afp[2], bfp[4];
  READ_A2(0, 0);
  READ_B2(32768, 0);
  READ_B2(32768, 1);

  DO_TILE(0, 1, 1, 1, 1, 4)
  DO_TILE(1, 1, 1, 1, 1, 4)
  DO_TILE(2, 1, 1, 1, 1, 4)
  DO_TILE(3, 1, 1, 1, 1, 4)
  DO_TILE(4, 1, 1, 1, 1, 4)
  DO_TILE(5, 1, 1, 1, 1, 4)
  DO_TILE(6, 1, 0, 1, 1, 0)
  DO_TILE(7, 0, 0, 0, 0, 0)

  // -------- epilogue: exp + diagonal mask + row/col partial sums --------
  float rsum[8][4];
  float csum[4];
#pragma unroll
  for (int m = 0; m < 8; m++)
#pragma unroll
    for (int j = 0; j < 4; j++) rsum[m][j] = 0.f;
#pragma unroll
  for (int n = 0; n < 4; n++) csum[n] = 0.f;

  const int col16 = l & 15, rgp = (l >> 4) & 3;
  const bool diag = (rb == cb);
  const int growbase = wr * 128 + rgp * 4;
  const int gcolbase = wc * 64 + col16;
#pragma unroll
  for (int m = 0; m < 8; m++) {
#pragma unroll
    for (int n = 0; n < 4; n++) {
#pragma unroll
      for (int j = 0; j < 4; j++) {
        const float e = (diag && (growbase + m * 16 + j) == (gcolbase + n * 16))
                            ? 0.f
                            : exp2f(acc[m][n][j] * EXPSCALE);
        rsum[m][j] += e;
        csum[n] += e;
      }
    }
  }
#pragma unroll
  for (int m = 0; m < 8; m++)
#pragma unroll
    for (int j = 0; j < 4; j++) {
      float v = rsum[m][j];
      v += __shfl_xor(v, 1); v += __shfl_xor(v, 2);
      v += __shfl_xor(v, 4); v += __shfl_xor(v, 8);
      rsum[m][j] = v;
    }
#pragma unroll
  for (int n = 0; n < 4; n++) {
    float v = csum[n];
    v += __shfl_xor(v, 16); v += __shfl_xor(v, 32);
    csum[n] = v;
  }

  float* rS = (float*)smem;            // [4 wc][256 rows]
  float* cS = ((float*)smem) + 1024;   // [2 wr][256 cols]
  if (col16 == 0) {
#pragma unroll
    for (int m = 0; m < 8; m++)
#pragma unroll
      for (int j = 0; j < 4; j++)
        rS[wc * 256 + wr * 128 + m * 16 + rgp * 4 + j] = rsum[m][j];
  }
  if (rgp == 0) {
#pragma unroll
    for (int n = 0; n < 4; n++)
      cS[wr * 256 + wc * 64 + n * 16 + col16] = csum[n];
  }
  __syncthreads();
  // partial layout: [68 col-blocks of 128][8192 rows]
  if (t < 256) {
    const float rs_lo = rS[t] + rS[256 + t];
    const float rs_hi = rS[512 + t] + rS[768 + t];
    partial[(size_t)(cb * 2) * N2 + rb * 256 + t] = rs_lo;
    partial[(size_t)(cb * 2 + 1) * N2 + rb * 256 + t] = rs_hi;
    if (!diag) {
      partial[(size_t)(rb * 2) * N2 + cb * 256 + t] = cS[t];
      partial[(size_t)(rb * 2 + 1) * N2 + cb * 256 + t] = cS[256 + t];
    }
  }
}

// ---------------- Kernel C1: per-row denom; log; block sum --------------------------------
__device__ inline float blockReduce(float v, float* sred) {
#pragma unroll
  for (int o = 32; o > 0; o >>= 1) v += __shfl_xor(v, o);
  const int lane = threadIdx.x & 63, wid = threadIdx.x >> 6;
  if (lane == 0) sred[wid] = v;
  __syncthreads();
  v = sred[0] + sred[1] + sred[2] + sred[3];
  __syncthreads();
  return v;
}

__global__ __launch_bounds__(256) void kred1(const float* __restrict__ partial,
                                             float* __restrict__ bsum) {
  const int r = blockIdx.x * 256 + threadIdx.x;
  float d = 0.f;
#pragma unroll 8
  for (int cbx = 0; cbx < 64; ++cbx) d += partial[(size_t)cbx * N2 + r];
  if (blockIdx.x >= 16) {   // rows >= 4096: add tail colsum slots 64..67
#pragma unroll
    for (int cbx = 64; cbx < 68; ++cbx) d += partial[(size_t)cbx * N2 + r];
  }
  float v = logf(d);
  __shared__ float sred[4];
  v = blockReduce(v, sred);
  if (threadIdx.x == 0) bsum[blockIdx.x] = v;
}

// ---------------- Kernel C2: final scalar -------------------------------------------------
__global__ __launch_bounds__(256) void kred2(const float* __restrict__ bsum,
                                             const float* __restrict__ pos,
                                             float* __restrict__ out) {
  const int t = threadIdx.x;
  float v = (t < 32) ? bsum[t] : 0.f;
  float p = 0.f;
  for (int k = t; k < BSZ; k += 256) p += pos[k];
  __shared__ float sred[4];
  v = blockReduce(v, sred);
  p = blockReduce(p, sred);
  if (t == 0) out[0] = (v - 2.0f * p / TEMPV) / (float)N2;
}

extern "C" void kernel_launch(void* const* d_in, const int* in_sizes, int n_in,
                              void* d_out, int out_size, void* d_ws, size_t ws_size,
                              hipStream_t stream) {
  const float* ei = (const float*)d_in[0];
  const float* ej = (const float*)d_in[1];
  char* ws = (char*)d_ws;
  unsigned char* reps8 = (unsigned char*)ws;                           // 8 MB fp8 [8192][1024]
  float* partial = (float*)(ws + (size_t)8 * 1024 * 1024);             // 2.13 MB [68][8192]
  float* pos = (float*)(ws + (size_t)8 * 1024 * 1024 + 2304 * 1024);   // 16 KB [4096]
  float* bsum = (float*)(ws + (size_t)8 * 1024 * 1024 + 2304 * 1024 + 16384); // 128 B

  (void)hipFuncSetAttribute((const void*)kgemm3,
                            hipFuncAttributeMaxDynamicSharedMemorySize, 131072);

  knorm<<<BSZ, 256, 0, stream>>>(ei, ej, reps8, pos);
  kgemm3<<<640, 512, 131072, stream>>>(reps8, partial);
  kred1<<<32, 256, 0, stream>>>(partial, bsum);
  kred2<<<1, 256, 0, stream>>>(bsum, pos, (float*)d_out);
}